// Round 3
// baseline (11209.860 us; speedup 1.0000x reference)
//
#include <hip/hip_runtime.h>
#include <stdint.h>

// ---------------- problem constants ----------------
#define B_SZ   256
#define SEQ_LEN 128
#define DIN    1024
#define DHID   2048
#define NCLS   1024
#define NBLK   256   // persistent grid = #CUs

typedef unsigned short ushort_t;
typedef short bf16x8 __attribute__((ext_vector_type(8)));
typedef float f32x16 __attribute__((ext_vector_type(16)));

__device__ __forceinline__ ushort_t f32_to_bf16(float f) {
  uint32_t u = __builtin_bit_cast(uint32_t, f);
  u = (u + 0x7FFFu + ((u >> 16) & 1u)) >> 16;
  return (ushort_t)u;
}
__device__ __forceinline__ float bf16_to_f32(ushort_t h) {
  uint32_t u = ((uint32_t)h) << 16;
  return __builtin_bit_cast(float, u);
}

// async global->LDS, 16B per lane. LDS dest must be WAVE-UNIFORM base; HW adds lane*16.
__device__ __forceinline__ void llds16(const ushort_t* g, ushort_t* l) {
  __builtin_amdgcn_global_load_lds(
      (const __attribute__((address_space(1))) void*)g,
      (__attribute__((address_space(3))) void*)l, 16, 0, 0);
}

// device-scope grid barrier (all NBLK blocks co-resident at 1 block/CU)
__device__ __forceinline__ void gsync(unsigned* cnt, unsigned target) {
  __syncthreads();
  if (threadIdx.x == 0) {
    __threadfence();  // release: drain stores, writeback L2
    __hip_atomic_fetch_add(cnt, 1u, __ATOMIC_RELEASE, __HIP_MEMORY_SCOPE_AGENT);
    while (__hip_atomic_load(cnt, __ATOMIC_ACQUIRE, __HIP_MEMORY_SCOPE_AGENT) < target)
      __builtin_amdgcn_s_sleep(16);
    __threadfence();  // acquire: invalidate caches
  }
  __syncthreads();
}

// ---------------- conversion kernels ----------------
__global__ void k_split(const float* __restrict__ s, ushort_t* __restrict__ hi,
                        ushort_t* __restrict__ lo, int n4) {
  int i = blockIdx.x * 256 + threadIdx.x;
  if (i >= n4) return;
  float4 v = ((const float4*)s)[i];
  ushort_t h0 = f32_to_bf16(v.x), h1 = f32_to_bf16(v.y);
  ushort_t h2 = f32_to_bf16(v.z), h3 = f32_to_bf16(v.w);
  ushort4 hv; hv.x = h0; hv.y = h1; hv.z = h2; hv.w = h3;
  ushort4 lv;
  lv.x = f32_to_bf16(v.x - bf16_to_f32(h0));
  lv.y = f32_to_bf16(v.y - bf16_to_f32(h1));
  lv.z = f32_to_bf16(v.z - bf16_to_f32(h2));
  lv.w = f32_to_bf16(v.w - bf16_to_f32(h3));
  ((ushort4*)hi)[i] = hv;
  ((ushort4*)lo)[i] = lv;
}

__global__ void k_cvt(const float* __restrict__ s, ushort_t* __restrict__ d, int n4) {
  int i = blockIdx.x * 256 + threadIdx.x;
  if (i >= n4) return;
  float4 v = ((const float4*)s)[i];
  ushort4 hv;
  hv.x = f32_to_bf16(v.x); hv.y = f32_to_bf16(v.y);
  hv.z = f32_to_bf16(v.z); hv.w = f32_to_bf16(v.w);
  ((ushort4*)d)[i] = hv;
}

// x [B,S,Din] fp32 -> x_t [S,B,Din] bf16 (transpose + convert)
__global__ void k_xT(const float* __restrict__ x, ushort_t* __restrict__ xt) {
  int m = blockIdx.x, t = blockIdx.y, tid = threadIdx.x;
  const float4* src = (const float4*)(x + ((size_t)m * SEQ_LEN + t) * DIN);
  ushort4* dst = (ushort4*)(xt + ((size_t)t * B_SZ + m) * DIN);
  float4 v = src[tid];
  ushort4 hv;
  hv.x = f32_to_bf16(v.x); hv.y = f32_to_bf16(v.y);
  hv.z = f32_to_bf16(v.z); hv.w = f32_to_bf16(v.w);
  dst[tid] = hv;
}

// ---------------- xproj GEMM: out[32768,2048] = x_t @ Whx^T + b_h (fp32 out) ---
// 128x128 tile, BK=64, 4 waves each 64x64 (2x2 frags of 32x32x16), dbuf llds16.
__global__ __launch_bounds__(256, 1) void k_xp(
    const ushort_t* __restrict__ A, const ushort_t* __restrict__ Bw,
    const float* __restrict__ bias, float* __restrict__ out) {
  __shared__ __align__(16) ushort_t lds[32768];  // 64KB: A 2x16KB @0B, B 2x16KB @32768B
  const int tid = threadIdx.x, lane = tid & 63, wv = tid >> 6;
  const int l31 = lane & 31, half = lane >> 5;
  const int bm0 = blockIdx.y * 128, bn0 = blockIdx.x * 128;

  f32x16 acc[2][2];
#pragma unroll
  for (int a = 0; a < 2; ++a)
#pragma unroll
    for (int c = 0; c < 2; ++c)
#pragma unroll
      for (int r = 0; r < 16; ++r) acc[a][c][r] = 0.0f;

  auto stage = [&](int buf, int kc) {
#pragma unroll
    for (int j = 0; j < 4; ++j) {
      int s = tid + 256 * j;
      int prow = s >> 3, glc = (s & 7) ^ (prow & 7);
      llds16(A + (size_t)(bm0 + prow) * DIN + (kc + glc * 8),
             &lds[(size_t)(buf * 16384 + (wv * 64 + 256 * j) * 16) / 2]);
      llds16(Bw + (size_t)(bn0 + prow) * DIN + (kc + glc * 8),
             &lds[(size_t)(32768 + buf * 16384 + (wv * 64 + 256 * j) * 16) / 2]);
    }
  };

  stage(0, 0);
  const int nit = DIN / 64;
  for (int i = 0; i < nit; ++i) {
    int buf = i & 1;
    if (i + 1 < nit) {
      stage(buf ^ 1, (i + 1) * 64);
      __builtin_amdgcn_s_waitcnt(0x3FF0 | 8);
    } else {
      __builtin_amdgcn_s_waitcnt(0x3FF0);
    }
    __builtin_amdgcn_s_barrier();
    const ushort_t* At = &lds[buf * 8192];
    const ushort_t* Bt = &lds[16384 + buf * 8192];
#pragma unroll
    for (int ks = 0; ks < 4; ++ks) {
      int ch = ks * 2 + half;
      bf16x8 af[2], bf_[2];
#pragma unroll
      for (int mi = 0; mi < 2; ++mi) {
        int row = (wv & 1) * 64 + mi * 32 + l31;
        int pch = ch ^ (row & 7);
        af[mi] = *(const bf16x8*)&At[row * 64 + pch * 8];
      }
#pragma unroll
      for (int ni = 0; ni < 2; ++ni) {
        int row = (wv >> 1) * 64 + ni * 32 + l31;
        int pch = ch ^ (row & 7);
        bf_[ni] = *(const bf16x8*)&Bt[row * 64 + pch * 8];
      }
#pragma unroll
      for (int mi = 0; mi < 2; ++mi)
#pragma unroll
        for (int ni = 0; ni < 2; ++ni)
          acc[mi][ni] = __builtin_amdgcn_mfma_f32_32x32x16_bf16(
              af[mi], bf_[ni], acc[mi][ni], 0, 0, 0);
    }
    __builtin_amdgcn_s_barrier();
  }

  int gm0 = bm0 + (wv & 1) * 64, gn0 = bn0 + (wv >> 1) * 64;
#pragma unroll
  for (int mi = 0; mi < 2; ++mi)
#pragma unroll
    for (int ni = 0; ni < 2; ++ni)
#pragma unroll
      for (int r = 0; r < 16; ++r) {
        int row = gm0 + mi * 32 + (r & 3) + 8 * (r >> 2) + 4 * half;
        int col = gn0 + ni * 32 + l31;
        out[(size_t)row * DHID + col] = acc[mi][ni][r] + bias[col];
      }
}

// ---------------- persistent recurrence kernel ----------------
// 256 blocks, 1/CU, 160KB LDS. Block b: kb=b&7 (k-slice 256), nb=(b>>3)&15
// (n-slice 128), mb=b>>7 (m-slice 128). Whh hi+lo slice pinned in LDS (128KB),
// h streamed via llds16 dbuf (32KB). Per step: phase A partials -> gsync ->
// phase B reduce+convert -> gsync.
__global__ __launch_bounds__(256, 1) void k_rnn(
    const ushort_t* __restrict__ whh_hi, const ushort_t* __restrict__ whh_lo,
    ushort_t* __restrict__ h_hi, ushort_t* __restrict__ h_lo,
    const float* __restrict__ xproj, float* __restrict__ P,
    unsigned* __restrict__ bar) {
  // bytes: W_hi [4 panels x 16KB] @0, W_lo @65536, A-stage 2x16KB @131072
  __shared__ __align__(16) ushort_t lds[81920];  // 160 KiB

  const int tid = threadIdx.x, lane = tid & 63, wv = tid >> 6;
  const int l31 = lane & 31, half = lane >> 5;
  const int b = blockIdx.x;
  const int kb = b & 7, nb = (b >> 3) & 15, mb = b >> 7;
  const int n0 = nb * 128, k0 = kb * 256, m0 = mb * 128;

  // ---- pin weight slices in LDS (once) ----
#pragma unroll
  for (int hl = 0; hl < 2; ++hl) {
    const ushort_t* W = hl ? whh_lo : whh_hi;
    for (int p = 0; p < 4; ++p)
#pragma unroll
      for (int j = 0; j < 4; ++j) {
        int s = tid + 256 * j;
        int prow = s >> 3, glc = (s & 7) ^ (prow & 7);
        const ushort_t* g = W + (size_t)(n0 + prow) * DHID + (k0 + p * 64 + glc * 8);
        ushort_t* d = &lds[(size_t)(hl * 65536 + p * 16384 + (wv * 64 + 256 * j) * 16) / 2];
        llds16(g, d);
      }
  }
  __builtin_amdgcn_s_waitcnt(0x3FF0);
  __syncthreads();

  auto stageA = [&](int buf, const ushort_t* src, int p) {
#pragma unroll
    for (int j = 0; j < 4; ++j) {
      int s = tid + 256 * j;
      int prow = s >> 3, glc = (s & 7) ^ (prow & 7);
      const ushort_t* g = src + (size_t)(m0 + prow) * DHID + (k0 + p * 64 + glc * 8);
      ushort_t* d = &lds[(size_t)(131072 + buf * 16384 + (wv * 64 + 256 * j) * 16) / 2];
      llds16(g, d);
    }
  };

  auto phaseB = [&](int t, bool withP) {
    const int r = b;
    const int c0 = tid * 8;
    const float* xp = xproj + ((size_t)t * B_SZ + r) * DHID + c0;
    float4 a0 = *(const float4*)xp;
    float4 a1 = *(const float4*)(xp + 4);
    float v[8] = {a0.x, a0.y, a0.z, a0.w, a1.x, a1.y, a1.z, a1.w};
    if (withP) {
#pragma unroll
      for (int k = 0; k < 8; ++k) {
        const float* pp = P + ((size_t)k * B_SZ + r) * DHID + c0;
        float4 p0 = *(const float4*)pp;
        float4 p1 = *(const float4*)(pp + 4);
        v[0] += p0.x; v[1] += p0.y; v[2] += p0.z; v[3] += p0.w;
        v[4] += p1.x; v[5] += p1.y; v[6] += p1.z; v[7] += p1.w;
      }
    }
    ushort_t hh[8], ll[8];
#pragma unroll
    for (int e = 0; e < 8; ++e) {
      hh[e] = f32_to_bf16(v[e]);
      ll[e] = f32_to_bf16(v[e] - bf16_to_f32(hh[e]));
    }
    ushort_t* dh = h_hi + (size_t)r * DHID + c0;
    ushort_t* dl = h_lo + (size_t)r * DHID + c0;
    *(ushort4*)dh = *(ushort4*)&hh[0];
    *(ushort4*)(dh + 4) = *(ushort4*)&hh[4];
    *(ushort4*)dl = *(ushort4*)&ll[0];
    *(ushort4*)(dl + 4) = *(ushort4*)&ll[4];
  };

  unsigned tgt = NBLK;
  phaseB(0, false);            // h_0 = xproj[0]
  gsync(bar, tgt); tgt += NBLK;

  for (int t = 1; t < SEQ_LEN; ++t) {
    // ---- phase A: partial[kb] += h_hi@W_hi + h_hi@W_lo + h_lo@W_hi over slab ----
    f32x16 acc[2][2];
#pragma unroll
    for (int a = 0; a < 2; ++a)
#pragma unroll
      for (int c = 0; c < 2; ++c)
#pragma unroll
        for (int r = 0; r < 16; ++r) acc[a][c][r] = 0.0f;

    stageA(0, h_hi, 0);
    for (int ci = 0; ci < 8; ++ci) {
      int buf = ci & 1;
      if (ci < 7) {
        stageA(buf ^ 1, (ci < 3) ? h_hi : h_lo, (ci + 1) & 3);
        __builtin_amdgcn_s_waitcnt(0x3FF0 | 4);
      } else {
        __builtin_amdgcn_s_waitcnt(0x3FF0);
      }
      __builtin_amdgcn_s_barrier();

      const ushort_t* At = &lds[(131072 + buf * 16384) / 2];
      const ushort_t* Bh = &lds[(size_t)((ci & 3) * 16384) / 2];
      const ushort_t* Bl = &lds[(size_t)(65536 + (ci & 3) * 16384) / 2];
      const bool isHi = ci < 4;  // A-tile is h_hi: do both W_hi and W_lo products
#pragma unroll
      for (int ks = 0; ks < 4; ++ks) {
        int ch = ks * 2 + half;
        bf16x8 af[2], bh_[2], bl_[2];
#pragma unroll
        for (int mi = 0; mi < 2; ++mi) {
          int row = (wv & 1) * 64 + mi * 32 + l31;
          int pch = ch ^ (row & 7);
          af[mi] = *(const bf16x8*)&At[row * 64 + pch * 8];
        }
#pragma unroll
        for (int ni = 0; ni < 2; ++ni) {
          int row = (wv >> 1) * 64 + ni * 32 + l31;
          int pch = ch ^ (row & 7);
          bh_[ni] = *(const bf16x8*)&Bh[row * 64 + pch * 8];
          if (isHi) bl_[ni] = *(const bf16x8*)&Bl[row * 64 + pch * 8];
        }
#pragma unroll
        for (int mi = 0; mi < 2; ++mi)
#pragma unroll
          for (int ni = 0; ni < 2; ++ni) {
            acc[mi][ni] = __builtin_amdgcn_mfma_f32_32x32x16_bf16(
                af[mi], bh_[ni], acc[mi][ni], 0, 0, 0);
            if (isHi)
              acc[mi][ni] = __builtin_amdgcn_mfma_f32_32x32x16_bf16(
                  af[mi], bl_[ni], acc[mi][ni], 0, 0, 0);
          }
      }
      __builtin_amdgcn_s_barrier();
    }

    // write partial tile
    {
      float* Pt = P + (size_t)kb * (B_SZ * DHID);
      int gm0 = m0 + (wv & 1) * 64, gn0 = n0 + (wv >> 1) * 64;
#pragma unroll
      for (int mi = 0; mi < 2; ++mi)
#pragma unroll
        for (int ni = 0; ni < 2; ++ni)
#pragma unroll
          for (int r = 0; r < 16; ++r) {
            int row = gm0 + mi * 32 + (r & 3) + 8 * (r >> 2) + 4 * half;
            int col = gn0 + ni * 32 + l31;
            Pt[(size_t)row * DHID + col] = acc[mi][ni][r];
          }
    }
    gsync(bar, tgt); tgt += NBLK;

    phaseB(t, true);
    gsync(bar, tgt); tgt += NBLK;
  }
}

// ---------------- readout GEMM (R2's segmented kernel, unchanged) -----------
struct Seg {
  const ushort_t* A;
  const ushort_t* B;
  int a_stride;
  int b_stride;
  int k_len;
};
struct Args {
  Seg seg[4];
  int n_seg;
  int n_iters;
  const float* bias;
  ushort_t* out_hi;
  ushort_t* out_lo;
  float* out_f32;
  int ldo;
};

#define DEPTH 6
__global__ __launch_bounds__(256, 1) void k_gemm(Args args) {
  __shared__ __align__(16) char pool[DEPTH * 12288];
  const int tid = threadIdx.x, lane = tid & 63, wv = tid >> 6;
  const int bm0 = blockIdx.y * 32, bn0 = blockIdx.x * 64;

  f32x16 acc[2];
#pragma unroll
  for (int c = 0; c < 2; ++c)
#pragma unroll
    for (int r = 0; r < 16; ++r) acc[c][r] = 0.0f;

  const int prow0 = tid >> 3;
  const int glc0 = (tid & 7) ^ (prow0 & 7);
  const int prow1 = (tid + 256) >> 3;
  const int glc1 = (tid & 7) ^ (prow1 & 7);

  auto stage = [&](int buf, const Seg& sg, int k0) {
    const ushort_t* ga = sg.A + (size_t)(bm0 + prow0) * sg.a_stride + (k0 + glc0 * 8);
    const ushort_t* gb0 = sg.B + (size_t)(bn0 + prow0) * sg.b_stride + (k0 + glc0 * 8);
    const ushort_t* gb1 = sg.B + (size_t)(bn0 + prow1) * sg.b_stride + (k0 + glc1 * 8);
    ushort_t* la = (ushort_t*)(pool + buf * 12288) + wv * 512;
    ushort_t* lb = (ushort_t*)(pool + buf * 12288 + 4096) + wv * 512;
    llds16(ga, la);
    llds16(gb0, lb);
    llds16(gb1, lb + 2048);
  };

  const int nit = args.n_iters;
  int sc = 0, kc = 0;
  int nst = nit < (DEPTH - 1) ? nit : (DEPTH - 1);
  for (int s = 0; s < nst; ++s) {
    stage(s, args.seg[sc], kc);
    kc += 64;
    if (kc >= args.seg[sc].k_len) { kc = 0; ++sc; }
  }

  const int half = lane >> 5, l31 = lane & 31;
  const int lch = wv * 2 + half;
  int sb = DEPTH - 1, cb = 0;

  for (int i = 0; i < nit; ++i) {
    int ahead = nit - 1 - i;
    if (ahead > DEPTH - 1) ahead = DEPTH - 1;
    if (i + DEPTH - 1 < nit) {
      stage(sb, args.seg[sc], kc);
      if (++sb == DEPTH) sb = 0;
      kc += 64;
      if (kc >= args.seg[sc].k_len) { kc = 0; ++sc; }
    }
    switch (ahead) {
      case 5: __builtin_amdgcn_s_waitcnt(0x3FF0 | 15); break;
      case 4: __builtin_amdgcn_s_waitcnt(0x3FF0 | 12); break;
      case 3: __builtin_amdgcn_s_waitcnt(0x3FF0 | 9); break;
      case 2: __builtin_amdgcn_s_waitcnt(0x3FF0 | 6); break;
      case 1: __builtin_amdgcn_s_waitcnt(0x3FF0 | 3); break;
      default: __builtin_amdgcn_s_waitcnt(0x3FF0 | 0); break;
    }
    __builtin_amdgcn_s_barrier();

    const ushort_t* tA = (const ushort_t*)(pool + cb * 12288);
    const ushort_t* tB = tA + 2048;
    bf16x8 af, bfm[2];
    {
      int row = l31;
      int pch = lch ^ (row & 7);
      af = *(const bf16x8*)&tA[row * 64 + pch * 8];
    }
#pragma unroll
    for (int ni = 0; ni < 2; ++ni) {
      int row = ni * 32 + l31;
      int pch = lch ^ (row & 7);
      bfm[ni] = *(const bf16x8*)&tB[row * 64 + pch * 8];
    }
#pragma unroll
    for (int ni = 0; ni < 2; ++ni)
      acc[ni] = __builtin_amdgcn_mfma_f32_32x32x16_bf16(af, bfm[ni], acc[ni], 0, 0, 0);

    if (++cb == DEPTH) cb = 0;
    __builtin_amdgcn_s_barrier();
  }

  __syncthreads();
  float* red = (float*)pool + wv * 2048;
#pragma unroll
  for (int ni = 0; ni < 2; ++ni)
#pragma unroll
    for (int r = 0; r < 16; ++r) {
      int row = (r & 3) + 8 * (r >> 2) + 4 * half;
      int col = ni * 32 + l31;
      red[row * 64 + col] = acc[ni][r];
    }
  __syncthreads();

  const float* r0 = (const float*)pool;
  const float* r1 = r0 + 2048;
  const float* r2 = r0 + 4096;
  const float* r3 = r0 + 6144;
#pragma unroll
  for (int j = 0; j < 8; ++j) {
    int e = j * 256 + tid;
    int row = e >> 6, col = e & 63;
    float v = r0[e] + r1[e] + r2[e] + r3[e] + args.bias[bn0 + col];
    size_t o = (size_t)(bm0 + row) * args.ldo + (bn0 + col);
    if (args.out_f32) {
      args.out_f32[o] = v;
    } else {
      ushort_t h = f32_to_bf16(v);
      args.out_hi[o] = h;
      args.out_lo[o] = f32_to_bf16(v - bf16_to_f32(h));
    }
  }
}

// ---------------- launch ----------------
extern "C" void kernel_launch(void* const* d_in, const int* in_sizes, int n_in,
                              void* d_out, int out_size, void* d_ws, size_t ws_size,
                              hipStream_t stream) {
  const float* x   = (const float*)d_in[0];
  const float* Whx = (const float*)d_in[1];
  const float* Whh = (const float*)d_in[2];
  const float* Wph = (const float*)d_in[3];
  const float* bh  = (const float*)d_in[4];
  const float* bp  = (const float*)d_in[5];

  char* p = (char*)d_ws;
  ushort_t* whh_hi = (ushort_t*)p; p += (size_t)DHID * DHID * 2;      // 8 MB
  ushort_t* whh_lo = (ushort_t*)p; p += (size_t)DHID * DHID * 2;      // 8 MB
  ushort_t* whx_b  = (ushort_t*)p; p += (size_t)DHID * DIN * 2;       // 4 MB
  ushort_t* wph_b  = (ushort_t*)p; p += (size_t)NCLS * DHID * 2;      // 4 MB
  ushort_t* x_t    = (ushort_t*)p; p += (size_t)SEQ_LEN * B_SZ * DIN * 2;   // 67 MB
  float*    xproj  = (float*)p;    p += (size_t)SEQ_LEN * B_SZ * DHID * 4;  // 268 MB
  float*    Part   = (float*)p;    p += (size_t)8 * B_SZ * DHID * 4;        // 16.8 MB
  ushort_t* h_hi   = (ushort_t*)p; p += (size_t)B_SZ * DHID * 2;            // 1 MB
  ushort_t* h_lo   = (ushort_t*)p; p += (size_t)B_SZ * DHID * 2;            // 1 MB
  unsigned* bar    = (unsigned*)p; p += 256;

  hipMemsetAsync(bar, 0, 256, stream);

  // conversions (ws re-poisoned every call -> redo every launch)
  {
    int n4 = DHID * DHID / 4;
    k_split<<<(n4 + 255) / 256, 256, 0, stream>>>(Whh, whh_hi, whh_lo, n4);
  }
  {
    int n4 = DHID * DIN / 4;
    k_cvt<<<(n4 + 255) / 256, 256, 0, stream>>>(Whx, whx_b, n4);
  }
  {
    int n4 = NCLS * DHID / 4;
    k_cvt<<<(n4 + 255) / 256, 256, 0, stream>>>(Wph, wph_b, n4);
  }
  k_xT<<<dim3(B_SZ, SEQ_LEN), 256, 0, stream>>>(x, x_t);

  // xproj for all timesteps: [S*B, DHID] fp32 (+b_h), rows ordered t*256+m
  k_xp<<<dim3(DHID / 128, (SEQ_LEN * B_SZ) / 128), 256, 0, stream>>>(
      x_t, whx_b, bh, xproj);

  // persistent recurrence
  k_rnn<<<dim3(NBLK), 256, 0, stream>>>(whh_hi, whh_lo, h_hi, h_lo, xproj, Part, bar);

  // readout: p = h_T @ Wph^T + b_p
  {
    Args a = {};
    a.seg[0] = { h_hi, wph_b, DHID, DHID, DHID };
    a.seg[1] = { h_lo, wph_b, DHID, DHID, DHID };
    a.n_seg = 2; a.n_iters = 2 * DHID / 64;
    a.bias = bp; a.out_hi = nullptr; a.out_lo = nullptr;
    a.out_f32 = (float*)d_out; a.ldo = NCLS;
    k_gemm<<<dim3(NCLS / 64, B_SZ / 32), 256, 0, stream>>>(a);
  }
}

// Round 4
// 4192.365 us; speedup vs baseline: 2.6739x; 2.6739x over previous
//
#include <hip/hip_runtime.h>
#include <stdint.h>

// ---------------- problem constants ----------------
#define B_SZ   256
#define SEQ_LEN 128
#define DIN    1024
#define DHID   2048
#define NCLS   1024
#define NBLK   256   // persistent grid = #CUs

// CPol bits on gfx940+/gfx950: SC0=1, NT=2, DLC=4, SC1=16
#define CPOL_SC0_SC1 17

typedef unsigned short ushort_t;
typedef short bf16x8 __attribute__((ext_vector_type(8)));
typedef float f32x16 __attribute__((ext_vector_type(16)));

__device__ __forceinline__ ushort_t f32_to_bf16(float f) {
  uint32_t u = __builtin_bit_cast(uint32_t, f);
  u = (u + 0x7FFFu + ((u >> 16) & 1u)) >> 16;
  return (ushort_t)u;
}
__device__ __forceinline__ float bf16_to_f32(ushort_t h) {
  uint32_t u = ((uint32_t)h) << 16;
  return __builtin_bit_cast(float, u);
}

// async global->LDS, 16B per lane. LDS dest must be WAVE-UNIFORM base.
__device__ __forceinline__ void llds16(const ushort_t* g, ushort_t* l) {
  __builtin_amdgcn_global_load_lds(
      (const __attribute__((address_space(1))) void*)g,
      (__attribute__((address_space(3))) void*)l, 16, 0, 0);
}
// device-coherent variant (sc0|sc1: bypass L1/L2, read at IC)
__device__ __forceinline__ void llds16c(const ushort_t* g, ushort_t* l) {
  __builtin_amdgcn_global_load_lds(
      (const __attribute__((address_space(1))) void*)g,
      (__attribute__((address_space(3))) void*)l, 16, 0, CPOL_SC0_SC1);
}

__device__ __forceinline__ void cstore_f32(float* p, float v) {
  __hip_atomic_store(p, v, __ATOMIC_RELAXED, __HIP_MEMORY_SCOPE_AGENT);
}
__device__ __forceinline__ void cstore_u64(void* p, uint64_t v) {
  __hip_atomic_store((uint64_t*)p, v, __ATOMIC_RELAXED, __HIP_MEMORY_SCOPE_AGENT);
}
__device__ __forceinline__ uint64_t cload_u64(const void* p) {
  return __hip_atomic_load((uint64_t*)p, __ATOMIC_RELAXED, __HIP_MEMORY_SCOPE_AGENT);
}

// fence-free grid barrier: __syncthreads drains each wave's vmcnt (release for
// write-through sc1 stores); 8 padded counters kill same-line RMW serialization.
__device__ __forceinline__ void gsync(unsigned* cnt, unsigned ep) {
  __syncthreads();
  if (threadIdx.x == 0) {
    __hip_atomic_fetch_add(&cnt[(blockIdx.x >> 5) * 32], 1u,
                           __ATOMIC_RELAXED, __HIP_MEMORY_SCOPE_AGENT);
    const unsigned tgt = ep * NBLK;
    for (;;) {
      unsigned s = 0;
#pragma unroll
      for (int i = 0; i < 8; ++i)
        s += __hip_atomic_load(&cnt[i * 32], __ATOMIC_RELAXED,
                               __HIP_MEMORY_SCOPE_AGENT);
      if (s >= tgt) break;
      __builtin_amdgcn_s_sleep(2);
    }
  }
  __syncthreads();
}

// ---------------- conversion kernels ----------------
__global__ void k_split(const float* __restrict__ s, ushort_t* __restrict__ hi,
                        ushort_t* __restrict__ lo, int n4) {
  int i = blockIdx.x * 256 + threadIdx.x;
  if (i >= n4) return;
  float4 v = ((const float4*)s)[i];
  ushort_t h0 = f32_to_bf16(v.x), h1 = f32_to_bf16(v.y);
  ushort_t h2 = f32_to_bf16(v.z), h3 = f32_to_bf16(v.w);
  ushort4 hv; hv.x = h0; hv.y = h1; hv.z = h2; hv.w = h3;
  ushort4 lv;
  lv.x = f32_to_bf16(v.x - bf16_to_f32(h0));
  lv.y = f32_to_bf16(v.y - bf16_to_f32(h1));
  lv.z = f32_to_bf16(v.z - bf16_to_f32(h2));
  lv.w = f32_to_bf16(v.w - bf16_to_f32(h3));
  ((ushort4*)hi)[i] = hv;
  ((ushort4*)lo)[i] = lv;
}

__global__ void k_cvt(const float* __restrict__ s, ushort_t* __restrict__ d, int n4) {
  int i = blockIdx.x * 256 + threadIdx.x;
  if (i >= n4) return;
  float4 v = ((const float4*)s)[i];
  ushort4 hv;
  hv.x = f32_to_bf16(v.x); hv.y = f32_to_bf16(v.y);
  hv.z = f32_to_bf16(v.z); hv.w = f32_to_bf16(v.w);
  ((ushort4*)d)[i] = hv;
}

// ---------------- xproj GEMM: out[t*256+m, :] = x[m,t,:] @ Whx^T + b_h ------
// A rows are row-permuted reads of x_bf [B,S,Din] (transpose folded in).
__global__ __launch_bounds__(256, 1) void k_xp(
    const ushort_t* __restrict__ A, const ushort_t* __restrict__ Bw,
    const float* __restrict__ bias, float* __restrict__ out) {
  __shared__ __align__(16) ushort_t lds[32768];  // 64KB
  const int tid = threadIdx.x, lane = tid & 63, wv = tid >> 6;
  const int l31 = lane & 31, half = lane >> 5;
  const int bm0 = blockIdx.y * 128, bn0 = blockIdx.x * 128;
  const int t_ = bm0 >> 8, m0_ = bm0 & 255;  // 128-row tile lies in one t

  f32x16 acc[2][2];
#pragma unroll
  for (int a = 0; a < 2; ++a)
#pragma unroll
    for (int c = 0; c < 2; ++c)
#pragma unroll
      for (int r = 0; r < 16; ++r) acc[a][c][r] = 0.0f;

  auto stage = [&](int buf, int kc) {
#pragma unroll
    for (int j = 0; j < 4; ++j) {
      int s = tid + 256 * j;
      int prow = s >> 3, glc = (s & 7) ^ (prow & 7);
      llds16(A + ((size_t)(m0_ + prow) * SEQ_LEN + t_) * DIN + (kc + glc * 8),
             &lds[(size_t)(buf * 16384 + (wv * 64 + 256 * j) * 16) / 2]);
      llds16(Bw + (size_t)(bn0 + prow) * DIN + (kc + glc * 8),
             &lds[(size_t)(32768 + buf * 16384 + (wv * 64 + 256 * j) * 16) / 2]);
    }
  };

  stage(0, 0);
  const int nit = DIN / 64;
  for (int i = 0; i < nit; ++i) {
    int buf = i & 1;
    if (i + 1 < nit) {
      stage(buf ^ 1, (i + 1) * 64);
      __builtin_amdgcn_s_waitcnt(0x3FF0 | 8);
    } else {
      __builtin_amdgcn_s_waitcnt(0x3FF0);
    }
    __builtin_amdgcn_s_barrier();
    const ushort_t* At = &lds[buf * 8192];
    const ushort_t* Bt = &lds[16384 + buf * 8192];
#pragma unroll
    for (int ks = 0; ks < 4; ++ks) {
      int ch = ks * 2 + half;
      bf16x8 af[2], bf_[2];
#pragma unroll
      for (int mi = 0; mi < 2; ++mi) {
        int row = (wv & 1) * 64 + mi * 32 + l31;
        int pch = ch ^ (row & 7);
        af[mi] = *(const bf16x8*)&At[row * 64 + pch * 8];
      }
#pragma unroll
      for (int ni = 0; ni < 2; ++ni) {
        int row = (wv >> 1) * 64 + ni * 32 + l31;
        int pch = ch ^ (row & 7);
        bf_[ni] = *(const bf16x8*)&Bt[row * 64 + pch * 8];
      }
#pragma unroll
      for (int mi = 0; mi < 2; ++mi)
#pragma unroll
        for (int ni = 0; ni < 2; ++ni)
          acc[mi][ni] = __builtin_amdgcn_mfma_f32_32x32x16_bf16(
              af[mi], bf_[ni], acc[mi][ni], 0, 0, 0);
    }
    __builtin_amdgcn_s_barrier();
  }

  int gm0 = bm0 + (wv & 1) * 64, gn0 = bn0 + (wv >> 1) * 64;
#pragma unroll
  for (int mi = 0; mi < 2; ++mi)
#pragma unroll
    for (int ni = 0; ni < 2; ++ni)
#pragma unroll
      for (int r = 0; r < 16; ++r) {
        int row = gm0 + mi * 32 + (r & 3) + 8 * (r >> 2) + 4 * half;
        int col = gn0 + ni * 32 + l31;
        out[(size_t)row * DHID + col] = acc[mi][ni][r] + bias[col];
      }
}

// ---------------- persistent recurrence kernel ----------------
__global__ __launch_bounds__(256, 1) void k_rnn(
    const ushort_t* __restrict__ whh_hi, const ushort_t* __restrict__ whh_lo,
    ushort_t* __restrict__ h_hi, ushort_t* __restrict__ h_lo,
    const float* __restrict__ xproj, float* __restrict__ P,
    unsigned* __restrict__ bar) {
  // bytes: W_hi [4 panels x 16KB] @0, W_lo @65536, A-stage 2x16KB @131072
  __shared__ __align__(16) ushort_t lds[81920];  // 160 KiB

  const int tid = threadIdx.x, lane = tid & 63, wv = tid >> 6;
  const int l31 = lane & 31, half = lane >> 5;
  const int b = blockIdx.x;
  const int kb = b & 7, nb = (b >> 3) & 15, mb = b >> 7;
  const int n0 = nb * 128, k0 = kb * 256, m0 = mb * 128;

  // ---- pin weight slices in LDS (once; normal cache path) ----
#pragma unroll
  for (int hl = 0; hl < 2; ++hl) {
    const ushort_t* W = hl ? whh_lo : whh_hi;
    for (int p = 0; p < 4; ++p)
#pragma unroll
      for (int j = 0; j < 4; ++j) {
        int s = tid + 256 * j;
        int prow = s >> 3, glc = (s & 7) ^ (prow & 7);
        const ushort_t* g = W + (size_t)(n0 + prow) * DHID + (k0 + p * 64 + glc * 8);
        ushort_t* d = &lds[(size_t)(hl * 65536 + p * 16384 + (wv * 64 + 256 * j) * 16) / 2];
        llds16(g, d);
      }
  }
  __builtin_amdgcn_s_waitcnt(0x3FF0);
  __syncthreads();

  // h staging: device-coherent (bypass L1/L2 -> fresh from IC)
  auto stageA = [&](int buf, const ushort_t* src, int p) {
#pragma unroll
    for (int j = 0; j < 4; ++j) {
      int s = tid + 256 * j;
      int prow = s >> 3, glc = (s & 7) ^ (prow & 7);
      const ushort_t* g = src + (size_t)(m0 + prow) * DHID + (k0 + p * 64 + glc * 8);
      ushort_t* d = &lds[(size_t)(131072 + buf * 16384 + (wv * 64 + 256 * j) * 16) / 2];
      llds16c(g, d);
    }
  };

  auto phaseB = [&](int t, bool withP) {
    const int r = b;
    const int c0 = tid * 8;
    const float* xp = xproj + ((size_t)t * B_SZ + r) * DHID + c0;
    float4 a0 = *(const float4*)xp;
    float4 a1 = *(const float4*)(xp + 4);
    float v[8] = {a0.x, a0.y, a0.z, a0.w, a1.x, a1.y, a1.z, a1.w};
    if (withP) {
#pragma unroll
      for (int k = 0; k < 8; ++k) {
        const float* pp = P + ((size_t)k * B_SZ + r) * DHID + c0;
#pragma unroll
        for (int j = 0; j < 4; ++j) {
          uint64_t q = cload_u64((const uint64_t*)pp + j);
          float2 f = __builtin_bit_cast(float2, q);
          v[2 * j]     += f.x;
          v[2 * j + 1] += f.y;
        }
      }
    }
    ushort_t hh[8], ll[8];
#pragma unroll
    for (int e = 0; e < 8; ++e) {
      hh[e] = f32_to_bf16(v[e]);
      ll[e] = f32_to_bf16(v[e] - bf16_to_f32(hh[e]));
    }
    uint64_t q0, q1, q2, q3;
    __builtin_memcpy(&q0, &hh[0], 8);
    __builtin_memcpy(&q1, &hh[4], 8);
    __builtin_memcpy(&q2, &ll[0], 8);
    __builtin_memcpy(&q3, &ll[4], 8);
    ushort_t* dh = h_hi + (size_t)r * DHID + c0;
    ushort_t* dl = h_lo + (size_t)r * DHID + c0;
    cstore_u64(dh, q0);
    cstore_u64(dh + 4, q1);
    cstore_u64(dl, q2);
    cstore_u64(dl + 4, q3);
  };

  unsigned ep = 1;
  phaseB(0, false);            // h_0 = xproj[0]
  gsync(bar, ep); ++ep;

  for (int t = 1; t < SEQ_LEN; ++t) {
    // ---- phase A: partial[kb] = h_hi@W_hi + h_hi@W_lo + h_lo@W_hi (slab) ----
    f32x16 acc[2][2];
#pragma unroll
    for (int a = 0; a < 2; ++a)
#pragma unroll
      for (int c = 0; c < 2; ++c)
#pragma unroll
        for (int r = 0; r < 16; ++r) acc[a][c][r] = 0.0f;

    stageA(0, h_hi, 0);
    for (int ci = 0; ci < 8; ++ci) {
      int buf = ci & 1;
      if (ci < 7) {
        stageA(buf ^ 1, (ci < 3) ? h_hi : h_lo, (ci + 1) & 3);
        __builtin_amdgcn_s_waitcnt(0x3FF0 | 4);
      } else {
        __builtin_amdgcn_s_waitcnt(0x3FF0);
      }
      __builtin_amdgcn_s_barrier();

      const ushort_t* At = &lds[(131072 + buf * 16384) / 2];
      const ushort_t* Bh = &lds[(size_t)((ci & 3) * 16384) / 2];
      const ushort_t* Bl = &lds[(size_t)(65536 + (ci & 3) * 16384) / 2];
      const bool isHi = ci < 4;
#pragma unroll
      for (int ks = 0; ks < 4; ++ks) {
        int ch = ks * 2 + half;
        bf16x8 af[2], bh_[2], bl_[2];
#pragma unroll
        for (int mi = 0; mi < 2; ++mi) {
          int row = (wv & 1) * 64 + mi * 32 + l31;
          int pch = ch ^ (row & 7);
          af[mi] = *(const bf16x8*)&At[row * 64 + pch * 8];
        }
#pragma unroll
        for (int ni = 0; ni < 2; ++ni) {
          int row = (wv >> 1) * 64 + ni * 32 + l31;
          int pch = ch ^ (row & 7);
          bh_[ni] = *(const bf16x8*)&Bh[row * 64 + pch * 8];
          if (isHi) bl_[ni] = *(const bf16x8*)&Bl[row * 64 + pch * 8];
        }
#pragma unroll
        for (int mi = 0; mi < 2; ++mi)
#pragma unroll
          for (int ni = 0; ni < 2; ++ni) {
            acc[mi][ni] = __builtin_amdgcn_mfma_f32_32x32x16_bf16(
                af[mi], bh_[ni], acc[mi][ni], 0, 0, 0);
            if (isHi)
              acc[mi][ni] = __builtin_amdgcn_mfma_f32_32x32x16_bf16(
                  af[mi], bl_[ni], acc[mi][ni], 0, 0, 0);
          }
      }
      __builtin_amdgcn_s_barrier();
    }

    // write partial tile (device-coherent stores)
    {
      float* Pt = P + (size_t)kb * (B_SZ * DHID);
      int gm0 = m0 + (wv & 1) * 64, gn0 = n0 + (wv >> 1) * 64;
#pragma unroll
      for (int mi = 0; mi < 2; ++mi)
#pragma unroll
        for (int ni = 0; ni < 2; ++ni)
#pragma unroll
          for (int r = 0; r < 16; ++r) {
            int row = gm0 + mi * 32 + (r & 3) + 8 * (r >> 2) + 4 * half;
            int col = gn0 + ni * 32 + l31;
            cstore_f32(&Pt[(size_t)row * DHID + col], acc[mi][ni][r]);
          }
    }
    gsync(bar, ep); ++ep;

    phaseB(t, true);
    gsync(bar, ep); ++ep;
  }
}

// ---------------- readout GEMM (R2's segmented kernel) -----------
struct Seg {
  const ushort_t* A;
  const ushort_t* B;
  int a_stride;
  int b_stride;
  int k_len;
};
struct Args {
  Seg seg[4];
  int n_seg;
  int n_iters;
  const float* bias;
  ushort_t* out_hi;
  ushort_t* out_lo;
  float* out_f32;
  int ldo;
};

#define DEPTH 6
__global__ __launch_bounds__(256, 1) void k_gemm(Args args) {
  __shared__ __align__(16) char pool[DEPTH * 12288];
  const int tid = threadIdx.x, lane = tid & 63, wv = tid >> 6;
  const int bm0 = blockIdx.y * 32, bn0 = blockIdx.x * 64;

  f32x16 acc[2];
#pragma unroll
  for (int c = 0; c < 2; ++c)
#pragma unroll
    for (int r = 0; r < 16; ++r) acc[c][r] = 0.0f;

  const int prow0 = tid >> 3;
  const int glc0 = (tid & 7) ^ (prow0 & 7);
  const int prow1 = (tid + 256) >> 3;
  const int glc1 = (tid & 7) ^ (prow1 & 7);

  auto stage = [&](int buf, const Seg& sg, int k0) {
    const ushort_t* ga = sg.A + (size_t)(bm0 + prow0) * sg.a_stride + (k0 + glc0 * 8);
    const ushort_t* gb0 = sg.B + (size_t)(bn0 + prow0) * sg.b_stride + (k0 + glc0 * 8);
    const ushort_t* gb1 = sg.B + (size_t)(bn0 + prow1) * sg.b_stride + (k0 + glc1 * 8);
    ushort_t* la = (ushort_t*)(pool + buf * 12288) + wv * 512;
    ushort_t* lb = (ushort_t*)(pool + buf * 12288 + 4096) + wv * 512;
    llds16(ga, la);
    llds16(gb0, lb);
    llds16(gb1, lb + 2048);
  };

  const int nit = args.n_iters;
  int sc = 0, kc = 0;
  int nst = nit < (DEPTH - 1) ? nit : (DEPTH - 1);
  for (int s = 0; s < nst; ++s) {
    stage(s, args.seg[sc], kc);
    kc += 64;
    if (kc >= args.seg[sc].k_len) { kc = 0; ++sc; }
  }

  const int half = lane >> 5, l31 = lane & 31;
  const int lch = wv * 2 + half;
  int sb = DEPTH - 1, cb = 0;

  for (int i = 0; i < nit; ++i) {
    int ahead = nit - 1 - i;
    if (ahead > DEPTH - 1) ahead = DEPTH - 1;
    if (i + DEPTH - 1 < nit) {
      stage(sb, args.seg[sc], kc);
      if (++sb == DEPTH) sb = 0;
      kc += 64;
      if (kc >= args.seg[sc].k_len) { kc = 0; ++sc; }
    }
    switch (ahead) {
      case 5: __builtin_amdgcn_s_waitcnt(0x3FF0 | 15); break;
      case 4: __builtin_amdgcn_s_waitcnt(0x3FF0 | 12); break;
      case 3: __builtin_amdgcn_s_waitcnt(0x3FF0 | 9); break;
      case 2: __builtin_amdgcn_s_waitcnt(0x3FF0 | 6); break;
      case 1: __builtin_amdgcn_s_waitcnt(0x3FF0 | 3); break;
      default: __builtin_amdgcn_s_waitcnt(0x3FF0 | 0); break;
    }
    __builtin_amdgcn_s_barrier();

    const ushort_t* tA = (const ushort_t*)(pool + cb * 12288);
    const ushort_t* tB = tA + 2048;
    bf16x8 af, bfm[2];
    {
      int row = l31;
      int pch = lch ^ (row & 7);
      af = *(const bf16x8*)&tA[row * 64 + pch * 8];
    }
#pragma unroll
    for (int ni = 0; ni < 2; ++ni) {
      int row = ni * 32 + l31;
      int pch = lch ^ (row & 7);
      bfm[ni] = *(const bf16x8*)&tB[row * 64 + pch * 8];
    }
#pragma unroll
    for (int ni = 0; ni < 2; ++ni)
      acc[ni] = __builtin_amdgcn_mfma_f32_32x32x16_bf16(af, bfm[ni], acc[ni], 0, 0, 0);

    if (++cb == DEPTH) cb = 0;
    __builtin_amdgcn_s_barrier();
  }

  __syncthreads();
  float* red = (float*)pool + wv * 2048;
#pragma unroll
  for (int ni = 0; ni < 2; ++ni)
#pragma unroll
    for (int r = 0; r < 16; ++r) {
      int row = (r & 3) + 8 * (r >> 2) + 4 * half;
      int col = ni * 32 + l31;
      red[row * 64 + col] = acc[ni][r];
    }
  __syncthreads();

  const float* r0 = (const float*)pool;
  const float* r1 = r0 + 2048;
  const float* r2 = r0 + 4096;
  const float* r3 = r0 + 6144;
#pragma unroll
  for (int j = 0; j < 8; ++j) {
    int e = j * 256 + tid;
    int row = e >> 6, col = e & 63;
    float v = r0[e] + r1[e] + r2[e] + r3[e] + args.bias[bn0 + col];
    size_t o = (size_t)(bm0 + row) * args.ldo + (bn0 + col);
    if (args.out_f32) {
      args.out_f32[o] = v;
    } else {
      ushort_t h = f32_to_bf16(v);
      args.out_hi[o] = h;
      args.out_lo[o] = f32_to_bf16(v - bf16_to_f32(h));
    }
  }
}

// ---------------- launch ----------------
extern "C" void kernel_launch(void* const* d_in, const int* in_sizes, int n_in,
                              void* d_out, int out_size, void* d_ws, size_t ws_size,
                              hipStream_t stream) {
  const float* x   = (const float*)d_in[0];
  const float* Whx = (const float*)d_in[1];
  const float* Whh = (const float*)d_in[2];
  const float* Wph = (const float*)d_in[3];
  const float* bh  = (const float*)d_in[4];
  const float* bp  = (const float*)d_in[5];

  char* p = (char*)d_ws;
  ushort_t* whh_hi = (ushort_t*)p; p += (size_t)DHID * DHID * 2;      // 8 MB
  ushort_t* whh_lo = (ushort_t*)p; p += (size_t)DHID * DHID * 2;      // 8 MB
  ushort_t* whx_b  = (ushort_t*)p; p += (size_t)DHID * DIN * 2;       // 4 MB
  ushort_t* wph_b  = (ushort_t*)p; p += (size_t)NCLS * DHID * 2;      // 4 MB
  ushort_t* x_b    = (ushort_t*)p; p += (size_t)B_SZ * SEQ_LEN * DIN * 2;   // 67 MB
  float*    xproj  = (float*)p;    p += (size_t)SEQ_LEN * B_SZ * DHID * 4;  // 268 MB
  float*    Part   = (float*)p;    p += (size_t)8 * B_SZ * DHID * 4;        // 16.8 MB
  ushort_t* h_hi   = (ushort_t*)p; p += (size_t)B_SZ * DHID * 2;            // 1 MB
  ushort_t* h_lo   = (ushort_t*)p; p += (size_t)B_SZ * DHID * 2;            // 1 MB
  unsigned* bar    = (unsigned*)p; p += 8 * 32 * 4;                         // 1 KB

  hipMemsetAsync(bar, 0, 8 * 32 * 4, stream);

  // conversions (ws re-poisoned every call -> redo every launch)
  {
    int n4 = DHID * DHID / 4;
    k_split<<<(n4 + 255) / 256, 256, 0, stream>>>(Whh, whh_hi, whh_lo, n4);
  }
  {
    int n4 = DHID * DIN / 4;
    k_cvt<<<(n4 + 255) / 256, 256, 0, stream>>>(Whx, whx_b, n4);
  }
  {
    int n4 = NCLS * DHID / 4;
    k_cvt<<<(n4 + 255) / 256, 256, 0, stream>>>(Wph, wph_b, n4);
  }
  {
    int n4 = B_SZ * SEQ_LEN * DIN / 4;
    k_cvt<<<(n4 + 255) / 256, 256, 0, stream>>>(x, x_b, n4);
  }

  // xproj for all timesteps: rows ordered t*256+m (x transpose folded in)
  k_xp<<<dim3(DHID / 128, (SEQ_LEN * B_SZ) / 128), 256, 0, stream>>>(
      x_b, whx_b, bh, xproj);

  // persistent recurrence
  k_rnn<<<dim3(NBLK), 256, 0, stream>>>(whh_hi, whh_lo, h_hi, h_lo, xproj, Part, bar);

  // readout: p = h_T @ Wph^T + b_p
  {
    Args a = {};
    a.seg[0] = { h_hi, wph_b, DHID, DHID, DHID };
    a.seg[1] = { h_lo, wph_b, DHID, DHID, DHID };
    a.n_seg = 2; a.n_iters = 2 * DHID / 64;
    a.bias = bp; a.out_hi = nullptr; a.out_lo = nullptr;
    a.out_f32 = (float*)d_out; a.ldo = NCLS;
    k_gemm<<<dim3(NCLS / 64, B_SZ / 32), 256, 0, stream>>>(a);
  }
}

// Round 5
// 3835.946 us; speedup vs baseline: 2.9223x; 1.0929x over previous
//
#include <hip/hip_runtime.h>
#include <stdint.h>

// ---------------- problem constants ----------------
#define B_SZ   256
#define SEQ_LEN 128
#define DIN    1024
#define DHID   2048
#define NCLS   1024
#define NBLK   256   // persistent grid = #CUs

// CPol bits on gfx940+/gfx950: SC0=1, NT=2, DLC=4, SC1=16
#define CPOL_SC0_SC1 17

typedef unsigned short ushort_t;
typedef short bf16x8 __attribute__((ext_vector_type(8)));
typedef float f32x16 __attribute__((ext_vector_type(16)));

__device__ __forceinline__ ushort_t f32_to_bf16(float f) {
  uint32_t u = __builtin_bit_cast(uint32_t, f);
  u = (u + 0x7FFFu + ((u >> 16) & 1u)) >> 16;
  return (ushort_t)u;
}
__device__ __forceinline__ float bf16_to_f32(ushort_t h) {
  uint32_t u = ((uint32_t)h) << 16;
  return __builtin_bit_cast(float, u);
}

// async global->LDS, 16B per lane (cached path; used for weight pinning only)
__device__ __forceinline__ void llds16(const ushort_t* g, ushort_t* l) {
  __builtin_amdgcn_global_load_lds(
      (const __attribute__((address_space(1))) void*)g,
      (__attribute__((address_space(3))) void*)l, 16, 0, 0);
}

__device__ __forceinline__ void cstore_f32(float* p, float v) {
  __hip_atomic_store(p, v, __ATOMIC_RELAXED, __HIP_MEMORY_SCOPE_AGENT);
}
__device__ __forceinline__ void cstore_u64(void* p, uint64_t v) {
  __hip_atomic_store((uint64_t*)p, v, __ATOMIC_RELAXED, __HIP_MEMORY_SCOPE_AGENT);
}
__device__ __forceinline__ uint64_t cload_u64(const void* p) {
  return __hip_atomic_load((const uint64_t*)p, __ATOMIC_RELAXED, __HIP_MEMORY_SCOPE_AGENT);
}

// fence-free grid barrier (validated in R4): __syncthreads drains each wave's
// vmcnt (release for write-through sc1 stores); 8 padded counters.
__device__ __forceinline__ void gsync(unsigned* cnt, unsigned ep) {
  __syncthreads();
  if (threadIdx.x == 0) {
    __hip_atomic_fetch_add(&cnt[(blockIdx.x >> 5) * 32], 1u,
                           __ATOMIC_RELAXED, __HIP_MEMORY_SCOPE_AGENT);
    const unsigned tgt = ep * NBLK;
    for (;;) {
      unsigned s = 0;
#pragma unroll
      for (int i = 0; i < 8; ++i)
        s += __hip_atomic_load(&cnt[i * 32], __ATOMIC_RELAXED,
                               __HIP_MEMORY_SCOPE_AGENT);
      if (s >= tgt) break;
      __builtin_amdgcn_s_sleep(2);
    }
  }
  __syncthreads();
}

// ---------------- conversion kernels ----------------
__global__ void k_split(const float* __restrict__ s, ushort_t* __restrict__ hi,
                        ushort_t* __restrict__ lo, int n4) {
  int i = blockIdx.x * 256 + threadIdx.x;
  if (i >= n4) return;
  float4 v = ((const float4*)s)[i];
  ushort_t h0 = f32_to_bf16(v.x), h1 = f32_to_bf16(v.y);
  ushort_t h2 = f32_to_bf16(v.z), h3 = f32_to_bf16(v.w);
  ushort4 hv; hv.x = h0; hv.y = h1; hv.z = h2; hv.w = h3;
  ushort4 lv;
  lv.x = f32_to_bf16(v.x - bf16_to_f32(h0));
  lv.y = f32_to_bf16(v.y - bf16_to_f32(h1));
  lv.z = f32_to_bf16(v.z - bf16_to_f32(h2));
  lv.w = f32_to_bf16(v.w - bf16_to_f32(h3));
  ((ushort4*)hi)[i] = hv;
  ((ushort4*)lo)[i] = lv;
}

__global__ void k_cvt(const float* __restrict__ s, ushort_t* __restrict__ d, int n4) {
  int i = blockIdx.x * 256 + threadIdx.x;
  if (i >= n4) return;
  float4 v = ((const float4*)s)[i];
  ushort4 hv;
  hv.x = f32_to_bf16(v.x); hv.y = f32_to_bf16(v.y);
  hv.z = f32_to_bf16(v.z); hv.w = f32_to_bf16(v.w);
  ((ushort4*)d)[i] = hv;
}

// ---------------- xproj GEMM: out[t*256+m, :] = x[m,t,:] @ Whx^T + b_h ------
__global__ __launch_bounds__(256, 1) void k_xp(
    const ushort_t* __restrict__ A, const ushort_t* __restrict__ Bw,
    const float* __restrict__ bias, float* __restrict__ out) {
  __shared__ __align__(16) ushort_t lds[32768];  // 64KB
  const int tid = threadIdx.x, lane = tid & 63, wv = tid >> 6;
  const int l31 = lane & 31, half = lane >> 5;
  const int bm0 = blockIdx.y * 128, bn0 = blockIdx.x * 128;
  const int t_ = bm0 >> 8, m0_ = bm0 & 255;  // 128-row tile lies in one t

  f32x16 acc[2][2];
#pragma unroll
  for (int a = 0; a < 2; ++a)
#pragma unroll
    for (int c = 0; c < 2; ++c)
#pragma unroll
      for (int r = 0; r < 16; ++r) acc[a][c][r] = 0.0f;

  auto stage = [&](int buf, int kc) {
#pragma unroll
    for (int j = 0; j < 4; ++j) {
      int s = tid + 256 * j;
      int prow = s >> 3, glc = (s & 7) ^ (prow & 7);
      llds16(A + ((size_t)(m0_ + prow) * SEQ_LEN + t_) * DIN + (kc + glc * 8),
             &lds[(size_t)(buf * 16384 + (wv * 64 + 256 * j) * 16) / 2]);
      llds16(Bw + (size_t)(bn0 + prow) * DIN + (kc + glc * 8),
             &lds[(size_t)(32768 + buf * 16384 + (wv * 64 + 256 * j) * 16) / 2]);
    }
  };

  stage(0, 0);
  const int nit = DIN / 64;
  for (int i = 0; i < nit; ++i) {
    int buf = i & 1;
    if (i + 1 < nit) {
      stage(buf ^ 1, (i + 1) * 64);
      __builtin_amdgcn_s_waitcnt(0x3FF0 | 8);
    } else {
      __builtin_amdgcn_s_waitcnt(0x3FF0);
    }
    __builtin_amdgcn_s_barrier();
    const ushort_t* At = &lds[buf * 8192];
    const ushort_t* Bt = &lds[16384 + buf * 8192];
#pragma unroll
    for (int ks = 0; ks < 4; ++ks) {
      int ch = ks * 2 + half;
      bf16x8 af[2], bf_[2];
#pragma unroll
      for (int mi = 0; mi < 2; ++mi) {
        int row = (wv & 1) * 64 + mi * 32 + l31;
        int pch = ch ^ (row & 7);
        af[mi] = *(const bf16x8*)&At[row * 64 + pch * 8];
      }
#pragma unroll
      for (int ni = 0; ni < 2; ++ni) {
        int row = (wv >> 1) * 64 + ni * 32 + l31;
        int pch = ch ^ (row & 7);
        bf_[ni] = *(const bf16x8*)&Bt[row * 64 + pch * 8];
      }
#pragma unroll
      for (int mi = 0; mi < 2; ++mi)
#pragma unroll
        for (int ni = 0; ni < 2; ++ni)
          acc[mi][ni] = __builtin_amdgcn_mfma_f32_32x32x16_bf16(
              af[mi], bf_[ni], acc[mi][ni], 0, 0, 0);
    }
    __builtin_amdgcn_s_barrier();
  }

  int gm0 = bm0 + (wv & 1) * 64, gn0 = bn0 + (wv >> 1) * 64;
#pragma unroll
  for (int mi = 0; mi < 2; ++mi)
#pragma unroll
    for (int ni = 0; ni < 2; ++ni)
#pragma unroll
      for (int r = 0; r < 16; ++r) {
        int row = gm0 + mi * 32 + (r & 3) + 8 * (r >> 2) + 4 * half;
        int col = gn0 + ni * 32 + l31;
        out[(size_t)row * DHID + col] = acc[mi][ni][r] + bias[col];
      }
}

// ---------------- persistent recurrence kernel (512 threads, 8 waves) -------
// Block b: kb=b&7 (k-slab 256), nb=(b>>3)&15 (n 128), mb=b>>7 (m 128).
// Waves: kslice=w&1 (k16-pair within 64-chunk), mq=(w>>1)&1, nq=w>>2.
// W hi/lo slab pinned in LDS (128KB). h staged per chunk via coherent u64
// register loads (lookahead 3 chunks) -> ds_write_b64 -> LDS dbuf (32KB);
// ONE __syncthreads per chunk. K-pair partials reduced in LDS, P exchanged
// fp32 via IC, phase B reduces 8 slabs + xproj -> h hi/lo.
__global__ __launch_bounds__(512, 2) void k_rnn(
    const ushort_t* __restrict__ whh_hi, const ushort_t* __restrict__ whh_lo,
    ushort_t* __restrict__ h_hi, ushort_t* __restrict__ h_lo,
    const float* __restrict__ xproj, float* __restrict__ P,
    unsigned* __restrict__ bar) {
  // bytes: W_hi [4 x 16KB] @0, W_lo @65536, h-stage dbuf 2x16KB @131072
  __shared__ __align__(16) ushort_t lds[81920];  // 160 KiB
  char* ldsb = (char*)&lds[0];

  const int tid = threadIdx.x, lane = tid & 63, wv = tid >> 6;
  const int l31 = lane & 31, half = lane >> 5;
  const int kslice = wv & 1, mq = (wv >> 1) & 1, nq = wv >> 2;
  const int b = blockIdx.x;
  const int kb = b & 7, nb = (b >> 3) & 15, mb = b >> 7;
  const int n0 = nb * 128, k0 = kb * 256, m0 = mb * 128;

  // ---- pin weight slices in LDS (once; cached path) ----
#pragma unroll
  for (int hl = 0; hl < 2; ++hl) {
    const ushort_t* W = hl ? whh_lo : whh_hi;
    for (int p = 0; p < 4; ++p)
#pragma unroll
      for (int j = 0; j < 2; ++j) {
        int s = tid + 512 * j;
        int prow = s >> 3, glc = (s & 7) ^ (prow & 7);
        const ushort_t* g = W + (size_t)(n0 + prow) * DHID + (k0 + p * 64 + glc * 8);
        ushort_t* d = (ushort_t*)(ldsb + hl * 65536 + p * 16384 + (wv * 64 + 512 * j) * 16);
        llds16(g, d);
      }
  }
  __builtin_amdgcn_s_waitcnt(0x3FF0);
  __syncthreads();

  // ---- staging constants: wave covers 16 rows; 4 u64 loads/chunk/thread ----
  const int srow0 = wv * 16 + (lane >> 4);   // tile-local row, +4*i per load
  const int skk   = 4 * (lane & 15);         // k element offset in row
  const int sg    = (lane & 15) >> 1;        // 16B chunk index of this u64
  const int ssub  = lane & 1;                // low/high half of chunk

  uint64_t R[4][4];

  auto regload = [&](int slot, int c) {
    const ushort_t* src = (c < 4) ? h_hi : h_lo;
    const int p = c & 3;
#pragma unroll
    for (int i = 0; i < 4; ++i)
      R[slot][i] = cload_u64(src + (size_t)(m0 + srow0 + 4 * i) * DHID +
                             (k0 + p * 64 + skk));
  };
  auto dswrite = [&](int buf, int slot) {
#pragma unroll
    for (int i = 0; i < 4; ++i) {
      int lr = srow0 + 4 * i;
      *(uint64_t*)(ldsb + 131072 + buf * 16384 + lr * 128 +
                   ((sg ^ (lr & 7)) * 16) + ssub * 8) = R[slot][i];
    }
  };

  auto phaseB = [&](int t, bool withP) {
    const int r = b;
    const int c0 = tid * 4;
    const float* xp = xproj + ((size_t)t * B_SZ + r) * DHID + c0;
    float4 a0 = *(const float4*)xp;
    float v[4] = {a0.x, a0.y, a0.z, a0.w};
    if (withP) {
#pragma unroll
      for (int k = 0; k < 8; ++k) {
        const float* pp = P + ((size_t)k * B_SZ + r) * DHID + c0;
#pragma unroll
        for (int j = 0; j < 2; ++j) {
          uint64_t q = cload_u64((const uint64_t*)pp + j);
          float2 f = __builtin_bit_cast(float2, q);
          v[2 * j]     += f.x;
          v[2 * j + 1] += f.y;
        }
      }
    }
    ushort_t hh[4], ll[4];
#pragma unroll
    for (int e = 0; e < 4; ++e) {
      hh[e] = f32_to_bf16(v[e]);
      ll[e] = f32_to_bf16(v[e] - bf16_to_f32(hh[e]));
    }
    uint64_t q0, q1;
    __builtin_memcpy(&q0, &hh[0], 8);
    __builtin_memcpy(&q1, &ll[0], 8);
    cstore_u64(h_hi + (size_t)r * DHID + c0, q0);
    cstore_u64(h_lo + (size_t)r * DHID + c0, q1);
  };

  unsigned ep = 1;
  phaseB(0, false);            // h_0 = xproj[0]
  gsync(bar, ep); ++ep;

  for (int t = 1; t < SEQ_LEN; ++t) {
    // ---- phase A ----
    f32x16 acc[2][2];
#pragma unroll
    for (int a = 0; a < 2; ++a)
#pragma unroll
      for (int c = 0; c < 2; ++c)
#pragma unroll
        for (int r = 0; r < 16; ++r) acc[a][c][r] = 0.0f;

    // prolog: prime 4 chunks of regs, write chunk0 to buf0
    regload(0, 0); regload(1, 1); regload(2, 2); regload(3, 3);
    dswrite(0, 0);
    __syncthreads();

    for (int c = 0; c < 8; ++c) {
      if (c + 4 <= 7) regload(c & 3, c + 4);
      if (c + 1 <= 7) dswrite((c + 1) & 1, (c + 1) & 3);

      const char* At = ldsb + 131072 + (c & 1) * 16384;
      const char* Bh = ldsb + (size_t)(c & 3) * 16384;
      const char* Bl = ldsb + 65536 + (size_t)(c & 3) * 16384;
      const bool isHi = c < 4;
#pragma unroll
      for (int ks = 0; ks < 2; ++ks) {
        const int g = (kslice * 2 + ks) * 2 + half;
        bf16x8 af[2], bh_[2], bl_[2];
#pragma unroll
        for (int mi = 0; mi < 2; ++mi) {
          int row = mq * 64 + mi * 32 + l31;
          af[mi] = *(const bf16x8*)(At + row * 128 + (g ^ (row & 7)) * 16);
        }
#pragma unroll
        for (int ni = 0; ni < 2; ++ni) {
          int row = nq * 64 + ni * 32 + l31;
          int off = row * 128 + (g ^ (row & 7)) * 16;
          bh_[ni] = *(const bf16x8*)(Bh + off);
          if (isHi) bl_[ni] = *(const bf16x8*)(Bl + off);
        }
#pragma unroll
        for (int mi = 0; mi < 2; ++mi)
#pragma unroll
          for (int ni = 0; ni < 2; ++ni) {
            acc[mi][ni] = __builtin_amdgcn_mfma_f32_32x32x16_bf16(
                af[mi], bh_[ni], acc[mi][ni], 0, 0, 0);
            if (isHi)
              acc[mi][ni] = __builtin_amdgcn_mfma_f32_32x32x16_bf16(
                  af[mi], bl_[ni], acc[mi][ni], 0, 0, 0);
          }
      }
      __syncthreads();
    }

    // ---- reduce kslice pairs through LDS (2 rounds over mi) ----
    {
      float* scr = (float*)(ldsb + 131072);  // 32KB
      const int pr = mq * 2 + nq;
#pragma unroll
      for (int r = 0; r < 2; ++r) {
        if (kslice == 1) {
#pragma unroll
          for (int ni = 0; ni < 2; ++ni)
#pragma unroll
            for (int reg = 0; reg < 16; ++reg) {
              int row32 = (reg & 3) + 8 * (reg >> 2) + 4 * half;
              scr[pr * 2048 + row32 * 64 + ni * 32 + l31] = acc[r][ni][reg];
            }
        }
        __syncthreads();
        if (kslice == 0) {
#pragma unroll
          for (int ni = 0; ni < 2; ++ni)
#pragma unroll
            for (int reg = 0; reg < 16; ++reg) {
              int row32 = (reg & 3) + 8 * (reg >> 2) + 4 * half;
              acc[r][ni][reg] += scr[pr * 2048 + row32 * 64 + ni * 32 + l31];
            }
        }
        __syncthreads();
      }
    }

    // ---- write partial tile (kslice0 waves only, device-coherent) ----
    if (kslice == 0) {
      float* Pt = P + (size_t)kb * (B_SZ * DHID);
#pragma unroll
      for (int mi = 0; mi < 2; ++mi)
#pragma unroll
        for (int ni = 0; ni < 2; ++ni)
#pragma unroll
          for (int reg = 0; reg < 16; ++reg) {
            int row = m0 + mq * 64 + mi * 32 + (reg & 3) + 8 * (reg >> 2) + 4 * half;
            int col = n0 + nq * 64 + ni * 32 + l31;
            cstore_f32(&Pt[(size_t)row * DHID + col], acc[mi][ni][reg]);
          }
    }
    gsync(bar, ep); ++ep;

    phaseB(t, true);
    gsync(bar, ep); ++ep;
  }
}

// ---------------- readout GEMM (R2's segmented kernel) -----------
struct Seg {
  const ushort_t* A;
  const ushort_t* B;
  int a_stride;
  int b_stride;
  int k_len;
};
struct Args {
  Seg seg[4];
  int n_seg;
  int n_iters;
  const float* bias;
  ushort_t* out_hi;
  ushort_t* out_lo;
  float* out_f32;
  int ldo;
};

#define DEPTH 6
__global__ __launch_bounds__(256, 1) void k_gemm(Args args) {
  __shared__ __align__(16) char pool[DEPTH * 12288];
  const int tid = threadIdx.x, lane = tid & 63, wv = tid >> 6;
  const int bm0 = blockIdx.y * 32, bn0 = blockIdx.x * 64;

  f32x16 acc[2];
#pragma unroll
  for (int c = 0; c < 2; ++c)
#pragma unroll
    for (int r = 0; r < 16; ++r) acc[c][r] = 0.0f;

  const int prow0 = tid >> 3;
  const int glc0 = (tid & 7) ^ (prow0 & 7);
  const int prow1 = (tid + 256) >> 3;
  const int glc1 = (tid & 7) ^ (prow1 & 7);

  auto stage = [&](int buf, const Seg& sg, int k0) {
    const ushort_t* ga = sg.A + (size_t)(bm0 + prow0) * sg.a_stride + (k0 + glc0 * 8);
    const ushort_t* gb0 = sg.B + (size_t)(bn0 + prow0) * sg.b_stride + (k0 + glc0 * 8);
    const ushort_t* gb1 = sg.B + (size_t)(bn0 + prow1) * sg.b_stride + (k0 + glc1 * 8);
    ushort_t* la = (ushort_t*)(pool + buf * 12288) + wv * 512;
    ushort_t* lb = (ushort_t*)(pool + buf * 12288 + 4096) + wv * 512;
    llds16(ga, la);
    llds16(gb0, lb);
    llds16(gb1, lb + 2048);
  };

  const int nit = args.n_iters;
  int sc = 0, kc = 0;
  int nst = nit < (DEPTH - 1) ? nit : (DEPTH - 1);
  for (int s = 0; s < nst; ++s) {
    stage(s, args.seg[sc], kc);
    kc += 64;
    if (kc >= args.seg[sc].k_len) { kc = 0; ++sc; }
  }

  const int half = lane >> 5, l31 = lane & 31;
  const int lch = wv * 2 + half;
  int sb = DEPTH - 1, cb = 0;

  for (int i = 0; i < nit; ++i) {
    int ahead = nit - 1 - i;
    if (ahead > DEPTH - 1) ahead = DEPTH - 1;
    if (i + DEPTH - 1 < nit) {
      stage(sb, args.seg[sc], kc);
      if (++sb == DEPTH) sb = 0;
      kc += 64;
      if (kc >= args.seg[sc].k_len) { kc = 0; ++sc; }
    }
    switch (ahead) {
      case 5: __builtin_amdgcn_s_waitcnt(0x3FF0 | 15); break;
      case 4: __builtin_amdgcn_s_waitcnt(0x3FF0 | 12); break;
      case 3: __builtin_amdgcn_s_waitcnt(0x3FF0 | 9); break;
      case 2: __builtin_amdgcn_s_waitcnt(0x3FF0 | 6); break;
      case 1: __builtin_amdgcn_s_waitcnt(0x3FF0 | 3); break;
      default: __builtin_amdgcn_s_waitcnt(0x3FF0 | 0); break;
    }
    __builtin_amdgcn_s_barrier();

    const ushort_t* tA = (const ushort_t*)(pool + cb * 12288);
    const ushort_t* tB = tA + 2048;
    bf16x8 af, bfm[2];
    {
      int row = l31;
      int pch = lch ^ (row & 7);
      af = *(const bf16x8*)&tA[row * 64 + pch * 8];
    }
#pragma unroll
    for (int ni = 0; ni < 2; ++ni) {
      int row = ni * 32 + l31;
      int pch = lch ^ (row & 7);
      bfm[ni] = *(const bf16x8*)&tB[row * 64 + pch * 8];
    }
#pragma unroll
    for (int ni = 0; ni < 2; ++ni)
      acc[ni] = __builtin_amdgcn_mfma_f32_32x32x16_bf16(af, bfm[ni], acc[ni], 0, 0, 0);

    if (++cb == DEPTH) cb = 0;
    __builtin_amdgcn_s_barrier();
  }

  __syncthreads();
  float* red = (float*)pool + wv * 2048;
#pragma unroll
  for (int ni = 0; ni < 2; ++ni)
#pragma unroll
    for (int r = 0; r < 16; ++r) {
      int row = (r & 3) + 8 * (r >> 2) + 4 * half;
      int col = ni * 32 + l31;
      red[row * 64 + col] = acc[ni][r];
    }
  __syncthreads();

  const float* r0 = (const float*)pool;
  const float* r1 = r0 + 2048;
  const float* r2 = r0 + 4096;
  const float* r3 = r0 + 6144;
#pragma unroll
  for (int j = 0; j < 8; ++j) {
    int e = j * 256 + tid;
    int row = e >> 6, col = e & 63;
    float v = r0[e] + r1[e] + r2[e] + r3[e] + args.bias[bn0 + col];
    size_t o = (size_t)(bm0 + row) * args.ldo + (bn0 + col);
    if (args.out_f32) {
      args.out_f32[o] = v;
    } else {
      ushort_t h = f32_to_bf16(v);
      args.out_hi[o] = h;
      args.out_lo[o] = f32_to_bf16(v - bf16_to_f32(h));
    }
  }
}

// ---------------- launch ----------------
extern "C" void kernel_launch(void* const* d_in, const int* in_sizes, int n_in,
                              void* d_out, int out_size, void* d_ws, size_t ws_size,
                              hipStream_t stream) {
  const float* x   = (const float*)d_in[0];
  const float* Whx = (const float*)d_in[1];
  const float* Whh = (const float*)d_in[2];
  const float* Wph = (const float*)d_in[3];
  const float* bh  = (const float*)d_in[4];
  const float* bp  = (const float*)d_in[5];

  char* p = (char*)d_ws;
  ushort_t* whh_hi = (ushort_t*)p; p += (size_t)DHID * DHID * 2;      // 8 MB
  ushort_t* whh_lo = (ushort_t*)p; p += (size_t)DHID * DHID * 2;      // 8 MB
  ushort_t* whx_b  = (ushort_t*)p; p += (size_t)DHID * DIN * 2;       // 4 MB
  ushort_t* wph_b  = (ushort_t*)p; p += (size_t)NCLS * DHID * 2;      // 4 MB
  ushort_t* x_b    = (ushort_t*)p; p += (size_t)B_SZ * SEQ_LEN * DIN * 2;   // 67 MB
  float*    xproj  = (float*)p;    p += (size_t)SEQ_LEN * B_SZ * DHID * 4;  // 268 MB
  float*    Part   = (float*)p;    p += (size_t)8 * B_SZ * DHID * 4;        // 16.8 MB
  ushort_t* h_hi   = (ushort_t*)p; p += (size_t)B_SZ * DHID * 2;            // 1 MB
  ushort_t* h_lo   = (ushort_t*)p; p += (size_t)B_SZ * DHID * 2;            // 1 MB
  unsigned* bar    = (unsigned*)p; p += 8 * 32 * 4;                         // 1 KB

  hipMemsetAsync(bar, 0, 8 * 32 * 4, stream);

  // conversions (ws re-poisoned every call -> redo every launch)
  {
    int n4 = DHID * DHID / 4;
    k_split<<<(n4 + 255) / 256, 256, 0, stream>>>(Whh, whh_hi, whh_lo, n4);
  }
  {
    int n4 = DHID * DIN / 4;
    k_cvt<<<(n4 + 255) / 256, 256, 0, stream>>>(Whx, whx_b, n4);
  }
  {
    int n4 = NCLS * DHID / 4;
    k_cvt<<<(n4 + 255) / 256, 256, 0, stream>>>(Wph, wph_b, n4);
  }
  {
    int n4 = B_SZ * SEQ_LEN * DIN / 4;
    k_cvt<<<(n4 + 255) / 256, 256, 0, stream>>>(x, x_b, n4);
  }

  // xproj for all timesteps: rows ordered t*256+m (x transpose folded in)
  k_xp<<<dim3(DHID / 128, (SEQ_LEN * B_SZ) / 128), 256, 0, stream>>>(
      x_b, whx_b, bh, xproj);

  // persistent recurrence
  k_rnn<<<dim3(NBLK), 512, 0, stream>>>(whh_hi, whh_lo, h_hi, h_lo, xproj, Part, bar);

  // readout: p = h_T @ Wph^T + b_p
  {
    Args a = {};
    a.seg[0] = { h_hi, wph_b, DHID, DHID, DHID };
    a.seg[1] = { h_lo, wph_b, DHID, DHID, DHID };
    a.n_seg = 2; a.n_iters = 2 * DHID / 64;
    a.bias = bp; a.out_hi = nullptr; a.out_lo = nullptr;
    a.out_f32 = (float*)d_out; a.ldo = NCLS;
    k_gemm<<<dim3(NCLS / 64, B_SZ / 32), 256, 0, stream>>>(a);
  }
}

// Round 6
// 1551.801 us; speedup vs baseline: 7.2238x; 2.4719x over previous
//
#include <hip/hip_runtime.h>
#include <stdint.h>

// ---------------- problem constants ----------------
#define B_SZ   256
#define SEQ_LEN 128
#define DIN    1024
#define DHID   2048
#define NCLS   1024
#define NBLK   256   // persistent grid = #CUs
#define NROUND 16    // 8-step blocking: h_7, h_15, ..., h_127

typedef unsigned short ushort_t;
typedef short bf16x8 __attribute__((ext_vector_type(8)));
typedef float f32x16 __attribute__((ext_vector_type(16)));

__device__ __forceinline__ ushort_t f32_to_bf16(float f) {
  uint32_t u = __builtin_bit_cast(uint32_t, f);
  u = (u + 0x7FFFu + ((u >> 16) & 1u)) >> 16;
  return (ushort_t)u;
}
__device__ __forceinline__ float bf16_to_f32(ushort_t h) {
  uint32_t u = ((uint32_t)h) << 16;
  return __builtin_bit_cast(float, u);
}

// async global->LDS, 16B per lane (cached path)
__device__ __forceinline__ void llds16(const ushort_t* g, ushort_t* l) {
  __builtin_amdgcn_global_load_lds(
      (const __attribute__((address_space(1))) void*)g,
      (__attribute__((address_space(3))) void*)l, 16, 0, 0);
}

__device__ __forceinline__ void cstore_f32(float* p, float v) {
  __hip_atomic_store(p, v, __ATOMIC_RELAXED, __HIP_MEMORY_SCOPE_AGENT);
}
__device__ __forceinline__ void cstore_u64(void* p, uint64_t v) {
  __hip_atomic_store((uint64_t*)p, v, __ATOMIC_RELAXED, __HIP_MEMORY_SCOPE_AGENT);
}
__device__ __forceinline__ uint64_t cload_u64(const void* p) {
  return __hip_atomic_load((const uint64_t*)p, __ATOMIC_RELAXED, __HIP_MEMORY_SCOPE_AGENT);
}
__device__ __forceinline__ void cstore_u32(unsigned* p, unsigned v) {
  __hip_atomic_store(p, v, __ATOMIC_RELAXED, __HIP_MEMORY_SCOPE_AGENT);
}
__device__ __forceinline__ unsigned cload_u32(const unsigned* p) {
  return __hip_atomic_load(p, __ATOMIC_RELAXED, __HIP_MEMORY_SCOPE_AGENT);
}

// contention-free grid barrier: per-block flag STORE (no RMW serialization),
// wave0 polls all 256 flags (4 per lane), ballot-all. Release = compiler's
// vmcnt(0) drain at __syncthreads (validated R4/R5).
__device__ __forceinline__ void gsync(unsigned* flags, unsigned ep) {
  __syncthreads();
  if (threadIdx.x == 0) cstore_u32(&flags[blockIdx.x], ep);
  if (threadIdx.x < 64) {
    const unsigned* f = flags + threadIdx.x * 4;
    for (;;) {
      unsigned a = cload_u32(f + 0), b = cload_u32(f + 1);
      unsigned c = cload_u32(f + 2), d = cload_u32(f + 3);
      bool ok = (a >= ep) & (b >= ep) & (c >= ep) & (d >= ep);
      if (__ballot(ok) == ~0ull) break;
      __builtin_amdgcn_s_sleep(1);
    }
  }
  __syncthreads();
}

// ---------------- conversion / transpose kernels ----------------
__global__ void k_split(const float* __restrict__ s, ushort_t* __restrict__ hi,
                        ushort_t* __restrict__ lo, int n4) {
  int i = blockIdx.x * 256 + threadIdx.x;
  if (i >= n4) return;
  float4 v = ((const float4*)s)[i];
  ushort_t h0 = f32_to_bf16(v.x), h1 = f32_to_bf16(v.y);
  ushort_t h2 = f32_to_bf16(v.z), h3 = f32_to_bf16(v.w);
  ushort4 hv; hv.x = h0; hv.y = h1; hv.z = h2; hv.w = h3;
  ushort4 lv;
  lv.x = f32_to_bf16(v.x - bf16_to_f32(h0));
  lv.y = f32_to_bf16(v.y - bf16_to_f32(h1));
  lv.z = f32_to_bf16(v.z - bf16_to_f32(h2));
  lv.w = f32_to_bf16(v.w - bf16_to_f32(h3));
  ((ushort4*)hi)[i] = hv;
  ((ushort4*)lo)[i] = lv;
}

__global__ void k_cvt(const float* __restrict__ s, ushort_t* __restrict__ d, int n4) {
  int i = blockIdx.x * 256 + threadIdx.x;
  if (i >= n4) return;
  float4 v = ((const float4*)s)[i];
  ushort4 hv;
  hv.x = f32_to_bf16(v.x); hv.y = f32_to_bf16(v.y);
  hv.z = f32_to_bf16(v.z); hv.w = f32_to_bf16(v.w);
  ((ushort4*)d)[i] = hv;
}

// bf16 2048x2048 transpose, 64x64 tiles
__global__ void k_trb(const ushort_t* __restrict__ src, ushort_t* __restrict__ dst) {
  __shared__ ushort_t t[64][65];
  const int bx = blockIdx.x * 64, by = blockIdx.y * 64;
  const int c = threadIdx.x & 63, r0 = (threadIdx.x >> 6) * 16;
#pragma unroll
  for (int i = 0; i < 16; ++i)
    t[r0 + i][c] = src[(size_t)(by + r0 + i) * DHID + bx + c];
  __syncthreads();
#pragma unroll
  for (int i = 0; i < 16; ++i)
    dst[(size_t)(bx + r0 + i) * DHID + by + c] = t[c][r0 + i];
}

// ---------------- generic 128x128-tile GEMM (from validated k_xp) ----------
// C[M,2048] = sum_seg A_seg * B_seg^T (+bias[col] | +bf16 D), out bf16
// (optionally hi/lo split). A row r -> element offset (r>>8)*tA + (r&255)*sA.
// B is [2048, klen] row-major. grid (2048/128, M/128).
struct BigArgs {
  const ushort_t* A[3];
  const ushort_t* B[3];
  int nseg;
  int klen;
  size_t tA, sA;
  const ushort_t* D;   // bf16 D or null; row map (r>>8)*tD + (r&255)*2048
  size_t tD;
  const float* bias;   // or null
  ushort_t* out_hi;
  ushort_t* out_lo;    // or null
};

__global__ __launch_bounds__(256, 1) void k_big(BigArgs a) {
  __shared__ __align__(16) ushort_t lds[32768];  // 64KB: A dbuf @0, B dbuf @32768B
  const int tid = threadIdx.x, lane = tid & 63, wv = tid >> 6;
  const int l31 = lane & 31, half = lane >> 5;
  const int bm0 = blockIdx.y * 128, bn0 = blockIdx.x * 128;
  const int t_ = bm0 >> 8, mrem = bm0 & 255;
  const int kit = a.klen >> 6;

  f32x16 acc[2][2];
#pragma unroll
  for (int p = 0; p < 2; ++p)
#pragma unroll
    for (int q = 0; q < 2; ++q)
#pragma unroll
      for (int r = 0; r < 16; ++r) acc[p][q][r] = 0.0f;

  auto stage = [&](int buf, int i) {
    int seg = 0, ii = i;
    while (ii >= kit) { ii -= kit; ++seg; }
    const int kc = ii * 64;
    const ushort_t* Ab = a.A[seg];
    const ushort_t* Bb = a.B[seg];
#pragma unroll
    for (int j = 0; j < 4; ++j) {
      int s = tid + 256 * j;
      int prow = s >> 3, glc = (s & 7) ^ (prow & 7);
      llds16(Ab + (size_t)t_ * a.tA + (size_t)(mrem + prow) * a.sA + (kc + glc * 8),
             &lds[(size_t)(buf * 16384 + (wv * 64 + 256 * j) * 16) / 2]);
      llds16(Bb + (size_t)(bn0 + prow) * a.klen + (kc + glc * 8),
             &lds[(size_t)(32768 + buf * 16384 + (wv * 64 + 256 * j) * 16) / 2]);
    }
  };

  const int nit = a.nseg * kit;
  stage(0, 0);
  for (int i = 0; i < nit; ++i) {
    int buf = i & 1;
    if (i + 1 < nit) {
      stage(buf ^ 1, i + 1);
      __builtin_amdgcn_s_waitcnt(0x3FF0 | 8);
    } else {
      __builtin_amdgcn_s_waitcnt(0x3FF0);
    }
    __builtin_amdgcn_s_barrier();
    const ushort_t* At = &lds[buf * 8192];
    const ushort_t* Bt = &lds[16384 + buf * 8192];
#pragma unroll
    for (int ks = 0; ks < 4; ++ks) {
      int ch = ks * 2 + half;
      bf16x8 af[2], bf_[2];
#pragma unroll
      for (int mi = 0; mi < 2; ++mi) {
        int row = (wv & 1) * 64 + mi * 32 + l31;
        int pch = ch ^ (row & 7);
        af[mi] = *(const bf16x8*)&At[row * 64 + pch * 8];
      }
#pragma unroll
      for (int ni = 0; ni < 2; ++ni) {
        int row = (wv >> 1) * 64 + ni * 32 + l31;
        int pch = ch ^ (row & 7);
        bf_[ni] = *(const bf16x8*)&Bt[row * 64 + pch * 8];
      }
#pragma unroll
      for (int mi = 0; mi < 2; ++mi)
#pragma unroll
        for (int ni = 0; ni < 2; ++ni)
          acc[mi][ni] = __builtin_amdgcn_mfma_f32_32x32x16_bf16(
              af[mi], bf_[ni], acc[mi][ni], 0, 0, 0);
    }
    __builtin_amdgcn_s_barrier();
  }

  int gm0 = bm0 + (wv & 1) * 64, gn0 = bn0 + (wv >> 1) * 64;
#pragma unroll
  for (int mi = 0; mi < 2; ++mi)
#pragma unroll
    for (int ni = 0; ni < 2; ++ni)
#pragma unroll
      for (int r = 0; r < 16; ++r) {
        int row = gm0 + mi * 32 + (r & 3) + 8 * (r >> 2) + 4 * half;
        int col = gn0 + ni * 32 + l31;
        float v = acc[mi][ni][r];
        if (a.bias) v += a.bias[col];
        if (a.D)
          v += bf16_to_f32(a.D[(size_t)(row >> 8) * a.tD +
                               (size_t)(row & 255) * 2048 + col]);
        ushort_t hh = f32_to_bf16(v);
        a.out_hi[(size_t)row * 2048 + col] = hh;
        if (a.out_lo)
          a.out_lo[(size_t)row * 2048 + col] = f32_to_bf16(v - bf16_to_f32(hh));
      }
}

// ---------------- persistent recurrence kernel (512 threads, 8 waves) -------
// 15 rounds of h_{t+8} = z8 + h_t @ (W8)^T (hi/lo 3-product), W8 slab pinned
// in LDS; structure identical to validated R5 core.
__global__ __launch_bounds__(512, 2) void k_rnn(
    const ushort_t* __restrict__ w8_hi, const ushort_t* __restrict__ w8_lo,
    ushort_t* __restrict__ h_hi, ushort_t* __restrict__ h_lo,
    const ushort_t* __restrict__ z8, float* __restrict__ P,
    unsigned* __restrict__ flags) {
  __shared__ __align__(16) ushort_t lds[81920];  // 160 KiB
  char* ldsb = (char*)&lds[0];

  const int tid = threadIdx.x, lane = tid & 63, wv = tid >> 6;
  const int l31 = lane & 31, half = lane >> 5;
  const int kslice = wv & 1, mq = (wv >> 1) & 1, nq = wv >> 2;
  const int b = blockIdx.x;
  const int kb = b & 7, nb = (b >> 3) & 15, mb = b >> 7;
  const int n0 = nb * 128, k0 = kb * 256, m0 = mb * 128;

  // ---- pin W8 slices in LDS (once; cached path) ----
#pragma unroll
  for (int hl = 0; hl < 2; ++hl) {
    const ushort_t* W = hl ? w8_lo : w8_hi;
    for (int p = 0; p < 4; ++p)
#pragma unroll
      for (int j = 0; j < 2; ++j) {
        int s = tid + 512 * j;
        int prow = s >> 3, glc = (s & 7) ^ (prow & 7);
        const ushort_t* g = W + (size_t)(n0 + prow) * DHID + (k0 + p * 64 + glc * 8);
        ushort_t* d = (ushort_t*)(ldsb + hl * 65536 + p * 16384 + (wv * 64 + 512 * j) * 16);
        llds16(g, d);
      }
  }
  __builtin_amdgcn_s_waitcnt(0x3FF0);
  __syncthreads();

  // ---- staging constants: wave covers 16 rows; 4 u64 loads/chunk/thread ----
  const int srow0 = wv * 16 + (lane >> 4);
  const int skk   = 4 * (lane & 15);
  const int sg    = (lane & 15) >> 1;
  const int ssub  = lane & 1;

  uint64_t R[4][4];

  auto regload = [&](int slot, int c) {
    const ushort_t* src = (c < 4) ? h_hi : h_lo;
    const int p = c & 3;
#pragma unroll
    for (int i = 0; i < 4; ++i)
      R[slot][i] = cload_u64(src + (size_t)(m0 + srow0 + 4 * i) * DHID +
                             (k0 + p * 64 + skk));
  };
  auto dswrite = [&](int buf, int slot) {
#pragma unroll
    for (int i = 0; i < 4; ++i) {
      int lr = srow0 + 4 * i;
      *(uint64_t*)(ldsb + 131072 + buf * 16384 + lr * 128 +
                   ((sg ^ (lr & 7)) * 16) + ssub * 8) = R[slot][i];
    }
  };

  auto phaseB = [&](ushort4 zq, bool withP) {
    const int r = b;
    const int c0 = tid * 4;
    float v[4] = {bf16_to_f32(zq.x), bf16_to_f32(zq.y),
                  bf16_to_f32(zq.z), bf16_to_f32(zq.w)};
    if (withP) {
#pragma unroll
      for (int k = 0; k < 8; ++k) {
        const float* pp = P + ((size_t)k * B_SZ + r) * DHID + c0;
#pragma unroll
        for (int j = 0; j < 2; ++j) {
          uint64_t q = cload_u64((const uint64_t*)pp + j);
          float2 f = __builtin_bit_cast(float2, q);
          v[2 * j]     += f.x;
          v[2 * j + 1] += f.y;
        }
      }
    }
    ushort_t hh[4], ll[4];
#pragma unroll
    for (int e = 0; e < 4; ++e) {
      hh[e] = f32_to_bf16(v[e]);
      ll[e] = f32_to_bf16(v[e] - bf16_to_f32(hh[e]));
    }
    uint64_t q0, q1;
    __builtin_memcpy(&q0, &hh[0], 8);
    __builtin_memcpy(&q1, &ll[0], 8);
    cstore_u64(h_hi + (size_t)r * DHID + c0, q0);
    cstore_u64(h_lo + (size_t)r * DHID + c0, q1);
  };

  unsigned ep = 1;
  {
    ushort4 zq = *(const ushort4*)(z8 + (size_t)b * DHID + tid * 4);
    phaseB(zq, false);  // h_7 = z8[0]
  }
  gsync(flags, ep); ++ep;

  for (int j = 1; j < NROUND; ++j) {
    // ---- phase A: partial[kb] = h_hi@W8hi + h_hi@W8lo + h_lo@W8hi ----
    f32x16 acc[2][2];
#pragma unroll
    for (int p = 0; p < 2; ++p)
#pragma unroll
      for (int q = 0; q < 2; ++q)
#pragma unroll
        for (int r = 0; r < 16; ++r) acc[p][q][r] = 0.0f;

    regload(0, 0); regload(1, 1); regload(2, 2); regload(3, 3);
    dswrite(0, 0);
    __syncthreads();

    for (int c = 0; c < 8; ++c) {
      if (c + 4 <= 7) regload(c & 3, c + 4);
      if (c + 1 <= 7) dswrite((c + 1) & 1, (c + 1) & 3);

      const char* At = ldsb + 131072 + (c & 1) * 16384;
      const char* Bh = ldsb + (size_t)(c & 3) * 16384;
      const char* Bl = ldsb + 65536 + (size_t)(c & 3) * 16384;
      const bool isHi = c < 4;
#pragma unroll
      for (int ks = 0; ks < 2; ++ks) {
        const int g = (kslice * 2 + ks) * 2 + half;
        bf16x8 af[2], bh_[2], bl_[2];
#pragma unroll
        for (int mi = 0; mi < 2; ++mi) {
          int row = mq * 64 + mi * 32 + l31;
          af[mi] = *(const bf16x8*)(At + row * 128 + (g ^ (row & 7)) * 16);
        }
#pragma unroll
        for (int ni = 0; ni < 2; ++ni) {
          int row = nq * 64 + ni * 32 + l31;
          int off = row * 128 + (g ^ (row & 7)) * 16;
          bh_[ni] = *(const bf16x8*)(Bh + off);
          if (isHi) bl_[ni] = *(const bf16x8*)(Bl + off);
        }
#pragma unroll
        for (int mi = 0; mi < 2; ++mi)
#pragma unroll
          for (int ni = 0; ni < 2; ++ni) {
            acc[mi][ni] = __builtin_amdgcn_mfma_f32_32x32x16_bf16(
                af[mi], bh_[ni], acc[mi][ni], 0, 0, 0);
            if (isHi)
              acc[mi][ni] = __builtin_amdgcn_mfma_f32_32x32x16_bf16(
                  af[mi], bl_[ni], acc[mi][ni], 0, 0, 0);
          }
      }
      __syncthreads();
    }

    // ---- reduce kslice pairs through LDS ----
    {
      float* scr = (float*)(ldsb + 131072);
      const int pr = mq * 2 + nq;
#pragma unroll
      for (int r = 0; r < 2; ++r) {
        if (kslice == 1) {
#pragma unroll
          for (int ni = 0; ni < 2; ++ni)
#pragma unroll
            for (int reg = 0; reg < 16; ++reg) {
              int row32 = (reg & 3) + 8 * (reg >> 2) + 4 * half;
              scr[pr * 2048 + row32 * 64 + ni * 32 + l31] = acc[r][ni][reg];
            }
        }
        __syncthreads();
        if (kslice == 0) {
#pragma unroll
          for (int ni = 0; ni < 2; ++ni)
#pragma unroll
            for (int reg = 0; reg < 16; ++reg) {
              int row32 = (reg & 3) + 8 * (reg >> 2) + 4 * half;
              acc[r][ni][reg] += scr[pr * 2048 + row32 * 64 + ni * 32 + l31];
            }
        }
        __syncthreads();
      }
    }

    // ---- write partial tile (kslice0 waves, device-coherent) ----
    if (kslice == 0) {
      float* Pt = P + (size_t)kb * (B_SZ * DHID);
#pragma unroll
      for (int mi = 0; mi < 2; ++mi)
#pragma unroll
        for (int ni = 0; ni < 2; ++ni)
#pragma unroll
          for (int reg = 0; reg < 16; ++reg) {
            int row = m0 + mq * 64 + mi * 32 + (reg & 3) + 8 * (reg >> 2) + 4 * half;
            int col = n0 + nq * 64 + ni * 32 + l31;
            cstore_f32(&Pt[(size_t)row * DHID + col], acc[mi][ni][reg]);
          }
    }
    // prefetch this round's z row before the barrier (z8 is constant)
    ushort4 zq = *(const ushort4*)(z8 + ((size_t)j * 256 + b) * DHID + tid * 4);
    gsync(flags, ep); ++ep;

    phaseB(zq, true);
    gsync(flags, ep); ++ep;
  }
}

// ---------------- readout GEMM (validated R2 segmented kernel) -----------
struct Seg {
  const ushort_t* A;
  const ushort_t* B;
  int a_stride;
  int b_stride;
  int k_len;
};
struct Args {
  Seg seg[4];
  int n_seg;
  int n_iters;
  const float* bias;
  ushort_t* out_hi;
  ushort_t* out_lo;
  float* out_f32;
  int ldo;
};

#define DEPTH 6
__global__ __launch_bounds__(256, 1) void k_gemm(Args args) {
  __shared__ __align__(16) char pool[DEPTH * 12288];
  const int tid = threadIdx.x, lane = tid & 63, wv = tid >> 6;
  const int bm0 = blockIdx.y * 32, bn0 = blockIdx.x * 64;

  f32x16 acc[2];
#pragma unroll
  for (int c = 0; c < 2; ++c)
#pragma unroll
    for (int r = 0; r < 16; ++r) acc[c][r] = 0.0f;

  const int prow0 = tid >> 3;
  const int glc0 = (tid & 7) ^ (prow0 & 7);
  const int prow1 = (tid + 256) >> 3;
  const int glc1 = (tid & 7) ^ (prow1 & 7);

  auto stage = [&](int buf, const Seg& sg, int k0) {
    const ushort_t* ga = sg.A + (size_t)(bm0 + prow0) * sg.a_stride + (k0 + glc0 * 8);
    const ushort_t* gb0 = sg.B + (size_t)(bn0 + prow0) * sg.b_stride + (k0 + glc0 * 8);
    const ushort_t* gb1 = sg.B + (size_t)(bn0 + prow1) * sg.b_stride + (k0 + glc1 * 8);
    ushort_t* la = (ushort_t*)(pool + buf * 12288) + wv * 512;
    ushort_t* lb = (ushort_t*)(pool + buf * 12288 + 4096) + wv * 512;
    llds16(ga, la);
    llds16(gb0, lb);
    llds16(gb1, lb + 2048);
  };

  const int nit = args.n_iters;
  int sc = 0, kc = 0;
  int nst = nit < (DEPTH - 1) ? nit : (DEPTH - 1);
  for (int s = 0; s < nst; ++s) {
    stage(s, args.seg[sc], kc);
    kc += 64;
    if (kc >= args.seg[sc].k_len) { kc = 0; ++sc; }
  }

  const int half = lane >> 5, l31 = lane & 31;
  const int lch = wv * 2 + half;
  int sb = DEPTH - 1, cb = 0;

  for (int i = 0; i < nit; ++i) {
    int ahead = nit - 1 - i;
    if (ahead > DEPTH - 1) ahead = DEPTH - 1;
    if (i + DEPTH - 1 < nit) {
      stage(sb, args.seg[sc], kc);
      if (++sb == DEPTH) sb = 0;
      kc += 64;
      if (kc >= args.seg[sc].k_len) { kc = 0; ++sc; }
    }
    switch (ahead) {
      case 5: __builtin_amdgcn_s_waitcnt(0x3FF0 | 15); break;
      case 4: __builtin_amdgcn_s_waitcnt(0x3FF0 | 12); break;
      case 3: __builtin_amdgcn_s_waitcnt(0x3FF0 | 9); break;
      case 2: __builtin_amdgcn_s_waitcnt(0x3FF0 | 6); break;
      case 1: __builtin_amdgcn_s_waitcnt(0x3FF0 | 3); break;
      default: __builtin_amdgcn_s_waitcnt(0x3FF0 | 0); break;
    }
    __builtin_amdgcn_s_barrier();

    const ushort_t* tA = (const ushort_t*)(pool + cb * 12288);
    const ushort_t* tB = tA + 2048;
    bf16x8 af, bfm[2];
    {
      int row = l31;
      int pch = lch ^ (row & 7);
      af = *(const bf16x8*)&tA[row * 64 + pch * 8];
    }
#pragma unroll
    for (int ni = 0; ni < 2; ++ni) {
      int row = ni * 32 + l31;
      int pch = lch ^ (row & 7);
      bfm[ni] = *(const bf16x8*)&tB[row * 64 + pch * 8];
    }
#pragma unroll
    for (int ni = 0; ni < 2; ++ni)
      acc[ni] = __builtin_amdgcn_mfma_f32_32x32x16_bf16(af, bfm[ni], acc[ni], 0, 0, 0);

    if (++cb == DEPTH) cb = 0;
    __builtin_amdgcn_s_barrier();
  }

  __syncthreads();
  float* red = (float*)pool + wv * 2048;
#pragma unroll
  for (int ni = 0; ni < 2; ++ni)
#pragma unroll
    for (int r = 0; r < 16; ++r) {
      int row = (r & 3) + 8 * (r >> 2) + 4 * half;
      int col = ni * 32 + l31;
      red[row * 64 + col] = acc[ni][r];
    }
  __syncthreads();

  const float* r0 = (const float*)pool;
  const float* r1 = r0 + 2048;
  const float* r2 = r0 + 4096;
  const float* r3 = r0 + 6144;
#pragma unroll
  for (int j = 0; j < 8; ++j) {
    int e = j * 256 + tid;
    int row = e >> 6, col = e & 63;
    float v = r0[e] + r1[e] + r2[e] + r3[e] + args.bias[bn0 + col];
    size_t o = (size_t)(bm0 + row) * args.ldo + (bn0 + col);
    if (args.out_f32) {
      args.out_f32[o] = v;
    } else {
      ushort_t h = f32_to_bf16(v);
      args.out_hi[o] = h;
      args.out_lo[o] = f32_to_bf16(v - bf16_to_f32(h));
    }
  }
}

// ---------------- launch ----------------
extern "C" void kernel_launch(void* const* d_in, const int* in_sizes, int n_in,
                              void* d_out, int out_size, void* d_ws, size_t ws_size,
                              hipStream_t stream) {
  const float* x   = (const float*)d_in[0];
  const float* Whx = (const float*)d_in[1];
  const float* Whh = (const float*)d_in[2];
  const float* Wph = (const float*)d_in[3];
  const float* bh  = (const float*)d_in[4];
  const float* bp  = (const float*)d_in[5];

  const size_t WSZ = (size_t)DHID * DHID * 2;  // 8 MiB (one bf16 2048^2)
  char* p = (char*)d_ws;
  ushort_t* whh_hi = (ushort_t*)p; p += WSZ;
  ushort_t* whh_lo = (ushort_t*)p; p += WSZ;
  ushort_t* whhT_hi= (ushort_t*)p; p += WSZ;
  ushort_t* whhT_lo= (ushort_t*)p; p += WSZ;
  ushort_t* w2_hi  = (ushort_t*)p; p += WSZ;
  ushort_t* w2_lo  = (ushort_t*)p; p += WSZ;
  ushort_t* w4_hi  = (ushort_t*)p; p += WSZ;
  ushort_t* w4_lo  = (ushort_t*)p; p += WSZ;
  ushort_t* w8_hi  = (ushort_t*)p; p += WSZ;
  ushort_t* w8_lo  = (ushort_t*)p; p += WSZ;
  ushort_t* wT_hi  = (ushort_t*)p; p += WSZ;
  ushort_t* wT_lo  = (ushort_t*)p; p += WSZ;
  ushort_t* whx_b  = (ushort_t*)p; p += (size_t)DHID * DIN * 2;
  ushort_t* wph_b  = (ushort_t*)p; p += (size_t)NCLS * DHID * 2;
  ushort_t* x_b    = (ushort_t*)p; p += (size_t)B_SZ * SEQ_LEN * DIN * 2;   // 64 MiB
  ushort_t* xp_b   = (ushort_t*)p; p += (size_t)SEQ_LEN * B_SZ * DHID * 2;  // 128 MiB
  ushort_t* z2_b   = (ushort_t*)p; p += (size_t)64 * B_SZ * DHID * 2;       // 64 MiB
  ushort_t* z4_b   = (ushort_t*)p; p += (size_t)32 * B_SZ * DHID * 2;       // 32 MiB
  ushort_t* z8_b   = (ushort_t*)p; p += (size_t)16 * B_SZ * DHID * 2;       // 16 MiB
  float*    Part   = (float*)p;    p += (size_t)8 * B_SZ * DHID * 4;        // 16 MiB
  ushort_t* h_hi   = (ushort_t*)p; p += (size_t)B_SZ * DHID * 2;
  ushort_t* h_lo   = (ushort_t*)p; p += (size_t)B_SZ * DHID * 2;
  unsigned* flags  = (unsigned*)p; p += NBLK * 4;

  hipMemsetAsync(flags, 0, NBLK * 4, stream);

  // ---- conversions ----
  {
    int n4 = DHID * DHID / 4;
    k_split<<<(n4 + 255) / 256, 256, 0, stream>>>(Whh, whh_hi, whh_lo, n4);
  }
  k_trb<<<dim3(32, 32), 256, 0, stream>>>(whh_hi, whhT_hi);
  k_trb<<<dim3(32, 32), 256, 0, stream>>>(whh_lo, whhT_lo);
  {
    int n4 = DHID * DIN / 4;
    k_cvt<<<(n4 + 255) / 256, 256, 0, stream>>>(Whx, whx_b, n4);
  }
  {
    int n4 = NCLS * DHID / 4;
    k_cvt<<<(n4 + 255) / 256, 256, 0, stream>>>(Wph, wph_b, n4);
  }
  {
    int n4 = B_SZ * SEQ_LEN * DIN / 4;
    k_cvt<<<(n4 + 255) / 256, 256, 0, stream>>>(x, x_b, n4);
  }

  const size_t TBLK = (size_t)512 * DHID;  // two 256-row blocks (elements)

  // ---- xproj: xp[t*256+m] = x[m,t] @ Whx^T + b_h (bf16) ----
  {
    BigArgs a = {};
    a.A[0] = x_b; a.B[0] = whx_b; a.nseg = 1; a.klen = DIN;
    a.tA = DIN; a.sA = (size_t)SEQ_LEN * DIN;
    a.bias = bh; a.out_hi = xp_b;
    k_big<<<dim3(16, (SEQ_LEN * B_SZ) / 128), 256, 0, stream>>>(a);
  }
  // ---- W2 = Whh * Whh (3-product hi/lo), split out ----
  {
    BigArgs a = {};
    a.A[0] = whh_hi; a.B[0] = whhT_hi;
    a.A[1] = whh_hi; a.B[1] = whhT_lo;
    a.A[2] = whh_lo; a.B[2] = whhT_hi;
    a.nseg = 3; a.klen = DHID; a.tA = (size_t)256 * DHID; a.sA = DHID;
    a.out_hi = w2_hi; a.out_lo = w2_lo;
    k_big<<<dim3(16, 16), 256, 0, stream>>>(a);
  }
  // ---- z2[i] (t=2i+1): xp[2i]*W^T + xp[2i+1] ----
  {
    BigArgs a = {};
    a.A[0] = xp_b; a.B[0] = whh_hi; a.nseg = 1; a.klen = DHID;
    a.tA = TBLK; a.sA = DHID;
    a.D = xp_b + (size_t)256 * DHID; a.tD = TBLK;
    a.out_hi = z2_b;
    k_big<<<dim3(16, 128), 256, 0, stream>>>(a);
  }
  // ---- W4 = W2 * W2 ----
  k_trb<<<dim3(32, 32), 256, 0, stream>>>(w2_hi, wT_hi);
  k_trb<<<dim3(32, 32), 256, 0, stream>>>(w2_lo, wT_lo);
  {
    BigArgs a = {};
    a.A[0] = w2_hi; a.B[0] = wT_hi;
    a.A[1] = w2_hi; a.B[1] = wT_lo;
    a.A[2] = w2_lo; a.B[2] = wT_hi;
    a.nseg = 3; a.klen = DHID; a.tA = (size_t)256 * DHID; a.sA = DHID;
    a.out_hi = w4_hi; a.out_lo = w4_lo;
    k_big<<<dim3(16, 16), 256, 0, stream>>>(a);
  }
  // ---- z4[i] (t=4i+3): z2[2i]*W2^T + z2[2i+1] ----
  {
    BigArgs a = {};
    a.A[0] = z2_b; a.B[0] = w2_hi; a.nseg = 1; a.klen = DHID;
    a.tA = TBLK; a.sA = DHID;
    a.D = z2_b + (size_t)256 * DHID; a.tD = TBLK;
    a.out_hi = z4_b;
    k_big<<<dim3(16, 64), 256, 0, stream>>>(a);
  }
  // ---- W8 = W4 * W4 ----
  k_trb<<<dim3(32, 32), 256, 0, stream>>>(w4_hi, wT_hi);
  k_trb<<<dim3(32, 32), 256, 0, stream>>>(w4_lo, wT_lo);
  {
    BigArgs a = {};
    a.A[0] = w4_hi; a.B[0] = wT_hi;
    a.A[1] = w4_hi; a.B[1] = wT_lo;
    a.A[2] = w4_lo; a.B[2] = wT_hi;
    a.nseg = 3; a.klen = DHID; a.tA = (size_t)256 * DHID; a.sA = DHID;
    a.out_hi = w8_hi; a.out_lo = w8_lo;
    k_big<<<dim3(16, 16), 256, 0, stream>>>(a);
  }
  // ---- z8[i] (t=8i+7): z4[2i]*W4^T + z4[2i+1] ----
  {
    BigArgs a = {};
    a.A[0] = z4_b; a.B[0] = w4_hi; a.nseg = 1; a.klen = DHID;
    a.tA = TBLK; a.sA = DHID;
    a.D = z4_b + (size_t)256 * DHID; a.tD = TBLK;
    a.out_hi = z8_b;
    k_big<<<dim3(16, 32), 256, 0, stream>>>(a);
  }

  // ---- persistent recurrence: 15 rounds of 8 steps ----
  k_rnn<<<dim3(NBLK), 512, 0, stream>>>(w8_hi, w8_lo, h_hi, h_lo, z8_b, Part, flags);

  // ---- readout: p = h_127 @ Wph^T + b_p ----
  {
    Args a = {};
    a.seg[0] = { h_hi, wph_b, DHID, DHID, DHID };
    a.seg[1] = { h_lo, wph_b, DHID, DHID, DHID };
    a.n_seg = 2; a.n_iters = 2 * DHID / 64;
    a.bias = bp; a.out_hi = nullptr; a.out_lo = nullptr;
    a.out_f32 = (float*)d_out; a.ldo = NCLS;
    k_gemm<<<dim3(NCLS / 64, B_SZ / 32), 256, 0, stream>>>(a);
  }
}